// Round 2
// baseline (417.051 us; speedup 1.0000x reference)
//
#include <hip/hip_runtime.h>

// Problem constants
#define B_  4
#define S_  2048
#define D_  1024
#define H_  16
#define DH_ 64
#define M_  (B_*S_)   // 8192

typedef __bf16 bf8_t __attribute__((ext_vector_type(8)));
typedef float f4_t __attribute__((ext_vector_type(4)));
typedef unsigned short u16x8_t __attribute__((ext_vector_type(8)));

static __device__ __forceinline__ unsigned short f2bf(float f) {
  return __builtin_bit_cast(unsigned short, (__bf16)f);
}
static __device__ __forceinline__ bf8_t ldbf8(const unsigned short* p) {
  return __builtin_bit_cast(bf8_t, *(const u16x8_t*)p);
}
#define MFMA16(a,b,c) __builtin_amdgcn_mfma_f32_16x16x32_bf16((a),(b),(c),0,0,0)
#define GLDS16(gp, lp) __builtin_amdgcn_global_load_lds( \
    (const __attribute__((address_space(1))) void*)(gp), \
    (__attribute__((address_space(3))) void*)(lp), 16, 0, 0)

// 0.125 (1/sqrt(dh)) * log2(e): folded into Q so softmax uses bare exp2.
#define QSCALE 0.18033688011112042f

// ---------------- convert kernels ----------------

__global__ void cvt_x(const float* __restrict__ x, unsigned short* __restrict__ xb) {
  int i = blockIdx.x * 256 + threadIdx.x;            // over M_*D_/4
  float4 v = ((const float4*)x)[i];
  unsigned int lo = f2bf(v.x) | ((unsigned int)f2bf(v.y) << 16);
  unsigned int hi = f2bf(v.z) | ((unsigned int)f2bf(v.w) << 16);
  ((uint2*)xb)[i] = make_uint2(lo, hi);
}

// Wq/Wk/Wv are (H, D, DH). Build fused B^T weight: Wcat[n][k], n = qkv*1024 + h*64 + dh, k = d.
__global__ void cvt_wqkv(const float* __restrict__ Wq, const float* __restrict__ Wk,
                         const float* __restrict__ Wv, unsigned short* __restrict__ Wcat) {
  int i = blockIdx.x * 256 + threadIdx.x;            // over 3*1024*1024
  int qkv = i >> 20;
  int r   = i & ((1 << 20) - 1);
  int h   = r >> 16;
  int k   = (r & 65535) >> 6;
  int dh  = r & 63;
  const float* W = (qkv == 0) ? Wq : (qkv == 1 ? Wk : Wv);
  float v = W[r];                                    // r == h*65536 + k*64 + dh
  int n = qkv * 1024 + h * 64 + dh;
  Wcat[(size_t)n * 1024 + k] = f2bf(v);
}

// Wo is (D, D) row-major [d][n]. Build Wot[n][k=d].
__global__ void cvt_wo(const float* __restrict__ Wo, unsigned short* __restrict__ Wot) {
  int i = blockIdx.x * 256 + threadIdx.x;            // over 1024*1024
  int k = i >> 10, n = i & 1023;
  Wot[(size_t)n * 1024 + k] = f2bf(Wo[i]);
}

// ---------------- GEMM core (128x128 tile, BK=32, K=1024, B^T input) ----------------

static __device__ __forceinline__ void gemm_core(const unsigned short* __restrict__ A,
    const unsigned short* __restrict__ Bt, unsigned short* As, unsigned short* Bs,
    int bm, int bn, f4_t acc[4][4])
{
  const int tid = threadIdx.x, w = tid >> 6, lane = tid & 63;
  const int quad = lane >> 4, col = lane & 15;
  const int wm = (w >> 1) * 64, wn = (w & 1) * 64;
  const int srow = lane >> 2;                         // 0..15
  const int goff = (((lane & 3) ^ ((srow >> 1) & 3)) * 8);
  const unsigned short* ga = A  + (size_t)(bm + 32 * w + srow) * D_ + goff;
  const unsigned short* gb = Bt + (size_t)(bn + 32 * w + srow) * D_ + goff;
  unsigned short* lAs0 = &As[(32 * w) * 32];
  unsigned short* lAs1 = &As[(32 * w + 16) * 32];
  unsigned short* lBs0 = &Bs[(32 * w) * 32];
  unsigned short* lBs1 = &Bs[(32 * w + 16) * 32];
  const int psw = (quad ^ ((col >> 1) & 3)) * 8;

  for (int k0 = 0; k0 < D_; k0 += 32) {
    __syncthreads();
    GLDS16(ga + k0,           lAs0);
    GLDS16(ga + 16 * D_ + k0, lAs1);
    GLDS16(gb + k0,           lBs0);
    GLDS16(gb + 16 * D_ + k0, lBs1);
    __syncthreads();
    bf8_t af[4], bfv[4];
#pragma unroll
    for (int mt = 0; mt < 4; mt++) af[mt]  = ldbf8(&As[(wm + 16 * mt + col) * 32 + psw]);
#pragma unroll
    for (int nt = 0; nt < 4; nt++) bfv[nt] = ldbf8(&Bs[(wn + 16 * nt + col) * 32 + psw]);
#pragma unroll
    for (int mt = 0; mt < 4; mt++)
#pragma unroll
      for (int nt = 0; nt < 4; nt++)
        acc[mt][nt] = MFMA16(af[mt], bfv[nt], acc[mt][nt]);
  }
}

// ---------------- stage 1: QKV projection ----------------
// Q is pre-scaled by QSCALE (softmax scale folded in, exp2 base).

__global__ __launch_bounds__(256, 2) void gemm_qkv(const unsigned short* __restrict__ A,
    const unsigned short* __restrict__ Bt,
    unsigned short* __restrict__ Qp, unsigned short* __restrict__ Kp,
    unsigned short* __restrict__ Vtp)
{
  __shared__ __align__(16) unsigned short As[128 * 32];
  __shared__ __align__(16) unsigned short Bs[128 * 32];
  f4_t acc[4][4] = {};
  const int bm = blockIdx.y * 128, bn = blockIdx.x * 128;
  gemm_core(A, Bt, As, Bs, bm, bn, acc);

  const int tid = threadIdx.x, w = tid >> 6, lane = tid & 63;
  const int quad = lane >> 4, col = lane & 15;
  const int wm = (w >> 1) * 64, wn = (w & 1) * 64;
#pragma unroll
  for (int nt = 0; nt < 4; nt++) {
    int n = bn + wn + 16 * nt + col;
    int qkv = n >> 10, r1 = n & 1023, h = r1 >> 6, dh = r1 & 63;
#pragma unroll
    for (int mt = 0; mt < 4; mt++) {
      int m0 = bm + wm + 16 * mt + quad * 4;
      int b = m0 >> 11, s0 = m0 & 2047;
      if (qkv == 0) {
#pragma unroll
        for (int r = 0; r < 4; r++)
          Qp[((size_t)(b * H_ + h) * S_ + s0 + r) * DH_ + dh] = f2bf(acc[mt][nt][r] * QSCALE);
      } else if (qkv == 1) {
#pragma unroll
        for (int r = 0; r < 4; r++)
          Kp[((size_t)(b * H_ + h) * S_ + s0 + r) * DH_ + dh] = f2bf(acc[mt][nt][r]);
      } else {
        unsigned int lo = f2bf(acc[mt][nt][0]) | ((unsigned int)f2bf(acc[mt][nt][1]) << 16);
        unsigned int hi = f2bf(acc[mt][nt][2]) | ((unsigned int)f2bf(acc[mt][nt][3]) << 16);
        *(uint2*)&Vtp[((size_t)(b * H_ + h) * DH_ + dh) * S_ + s0] = make_uint2(lo, hi);
      }
    }
  }
}

// ---------------- stage 2: flash attention (no-max softmax, deferred l) ----------------
// Block = 128 Q-rows of one (b,h); wave w owns q-rows [32w,32w+32).
// Ks [sk][dh] (128x64, 16KB), Vs [dh][sk] (64x128, 16KB),
// Ps wave-private [32][64] halves (16KB total) -> 48KB LDS, 3 blocks/CU.

__global__ __launch_bounds__(256, 3) void flash_attn(const unsigned short* __restrict__ Qp,
    const unsigned short* __restrict__ Kp, const unsigned short* __restrict__ Vtp,
    unsigned short* __restrict__ Cc)
{
  __shared__ __align__(16) unsigned short Ks[128 * 64];
  __shared__ __align__(16) unsigned short Vs[64 * 128];
  __shared__ __align__(16) unsigned short Ps[4][32 * 64];
  const int tid = threadIdx.x, w = tid >> 6, lane = tid & 63;
  const int quad = lane >> 4, col = lane & 15;
  const int qt = blockIdx.x, bh = blockIdx.y;

  // Q fragments straight from global (A-layout: row = lane&15, k contiguous); pre-scaled
  const unsigned short* Qg = Qp + ((size_t)bh * S_ + qt * 128 + w * 32) * DH_;
  bf8_t aq[2][2];
#pragma unroll
  for (int t = 0; t < 2; t++)
#pragma unroll
    for (int kc = 0; kc < 2; kc++)
      aq[t][kc] = ldbf8(Qg + (t * 16 + col) * DH_ + kc * 32 + quad * 8);

  f4_t o[2][4] = {};
  float lp[2][4] = {};                                // per-lane partial softmax sums

  const unsigned short* Kg0 = Kp  + (size_t)bh * S_ * DH_;
  const unsigned short* Vg0 = Vtp + (size_t)bh * DH_ * S_;
  unsigned short* Pw = &Ps[w][0];

  for (int kt = 0; kt < S_ / 128; kt++) {
    __syncthreads();
    {
      const unsigned short* Kg = Kg0 + kt * 128 * DH_;
#pragma unroll
      for (int j = 0; j < 4; j++) {                       // K tile: 8 rows/instr
        int row = 32 * w + 8 * j + (lane >> 3);
        GLDS16(Kg + row * DH_ + (((lane & 7) ^ (row & 7)) * 8), &Ks[(32 * w + 8 * j) * 64]);
      }
#pragma unroll
      for (int j = 0; j < 4; j++) {                       // V^T tile: 4 rows/instr
        int row = 16 * w + 4 * j + (lane >> 4);
        GLDS16(Vg0 + (size_t)row * S_ + kt * 128 + (((lane & 15) ^ (row & 15)) * 8),
               &Vs[(16 * w + 4 * j) * 128]);
      }
    }
    __syncthreads();

    // S = Q K^T (scale pre-folded into Q); sc[t][ct]: q-rows t*16.., k-cols ct*16..
    f4_t sc[2][8] = {};
#pragma unroll
    for (int ct = 0; ct < 8; ct++) {
      int krow = ct * 16 + col;
#pragma unroll
      for (int kc = 0; kc < 2; kc++) {
        bf8_t bk = ldbf8(&Ks[krow * 64 + (((kc * 4 + quad) ^ (krow & 7)) * 8)]);
        sc[0][ct] = MFMA16(aq[0][kc], bk, sc[0][ct]);
        sc[1][ct] = MFMA16(aq[1][kc], bk, sc[1][ct]);
      }
    }

    // p = 2^s (no max tracking); accumulate per-lane l partials
#pragma unroll
    for (int t = 0; t < 2; t++)
#pragma unroll
      for (int ct = 0; ct < 8; ct++)
#pragma unroll
        for (int r = 0; r < 4; r++) {
          float p = __builtin_amdgcn_exp2f(sc[t][ct][r]);
          sc[t][ct][r] = p;
          lp[t][r] += p;
        }

    // O += P V in two k-halves; Ps is wave-private (no barrier needed)
#pragma unroll
    for (int hh = 0; hh < 2; hh++) {
#pragma unroll
      for (int t = 0; t < 2; t++)
#pragma unroll
        for (int r = 0; r < 4; r++) {
          int rho = t * 16 + quad * 4 + r;
#pragma unroll
          for (int ctl = 0; ctl < 4; ctl++) {
            int g = ctl * 2 + (col >> 3);
            Pw[rho * 64 + ((g ^ (rho & 7)) * 8) + (col & 7)] = f2bf(sc[t][hh * 4 + ctl][r]);
          }
        }
#pragma unroll
      for (int kcl = 0; kcl < 2; kcl++) {
        bf8_t ap0 = ldbf8(&Pw[(0 * 16 + col) * 64 + (((kcl * 4 + quad) ^ (col & 7)) * 8)]);
        bf8_t ap1 = ldbf8(&Pw[(1 * 16 + col) * 64 + (((kcl * 4 + quad) ^ (col & 7)) * 8)]);
        int gk = hh * 8 + kcl * 4 + quad;
#pragma unroll
        for (int cv = 0; cv < 4; cv++) {
          int vr = cv * 16 + col;
          bf8_t bv = ldbf8(&Vs[vr * 128 + ((gk ^ col) * 8)]);
          o[0][cv] = MFMA16(ap0, bv, o[0][cv]);
          o[1][cv] = MFMA16(ap1, bv, o[1][cv]);
        }
      }
    }
  }

  // final l: reduce per-lane partials across the 16 col-lanes (once)
  float l[2][4];
#pragma unroll
  for (int t = 0; t < 2; t++)
#pragma unroll
    for (int r = 0; r < 4; r++) {
      float s = lp[t][r];
#pragma unroll
      for (int off = 1; off < 16; off <<= 1) s += __shfl_xor(s, off);
      l[t][r] = s;
    }

  // epilogue: O/l -> concat (b, s, h*64+dh) bf16
  const int b = bh >> 4, h = bh & 15;
#pragma unroll
  for (int t = 0; t < 2; t++)
#pragma unroll
    for (int cv = 0; cv < 4; cv++)
#pragma unroll
      for (int r = 0; r < 4; r++) {
        float v = o[t][cv][r] / l[t][r];
        int s = qt * 128 + w * 32 + t * 16 + quad * 4 + r;
        int dcol = h * 64 + cv * 16 + col;
        Cc[((size_t)b * S_ + s) * D_ + dcol] = f2bf(v);
      }
}

// ---------------- stage 3: output projection ----------------

__global__ __launch_bounds__(256, 2) void gemm_out(const unsigned short* __restrict__ A,
    const unsigned short* __restrict__ Bt, float* __restrict__ Out)
{
  __shared__ __align__(16) unsigned short As[128 * 32];
  __shared__ __align__(16) unsigned short Bs[128 * 32];
  f4_t acc[4][4] = {};
  const int bm = blockIdx.y * 128, bn = blockIdx.x * 128;
  gemm_core(A, Bt, As, Bs, bm, bn, acc);

  const int tid = threadIdx.x, w = tid >> 6, lane = tid & 63;
  const int quad = lane >> 4, col = lane & 15;
  const int wm = (w >> 1) * 64, wn = (w & 1) * 64;
#pragma unroll
  for (int nt = 0; nt < 4; nt++) {
    int n = bn + wn + 16 * nt + col;
#pragma unroll
    for (int mt = 0; mt < 4; mt++) {
      int m0 = bm + wm + 16 * mt + quad * 4;
#pragma unroll
      for (int r = 0; r < 4; r++)
        Out[(size_t)(m0 + r) * D_ + n] = acc[mt][nt][r];
    }
  }
}

// ---------------- launch ----------------

extern "C" void kernel_launch(void* const* d_in, const int* in_sizes, int n_in,
                              void* d_out, int out_size, void* d_ws, size_t ws_size,
                              hipStream_t stream) {
  const float* x  = (const float*)d_in[0];
  const float* Wq = (const float*)d_in[1];
  const float* Wk = (const float*)d_in[2];
  const float* Wv = (const float*)d_in[3];
  const float* Wo = (const float*)d_in[4];
  float* out = (float*)d_out;

  char* ws = (char*)d_ws;
  size_t off = 0;
  auto alloc = [&](size_t bytes) -> void* {
    void* p = ws + off;
    off += (bytes + 255) & ~(size_t)255;
    return p;
  };
  unsigned short* xb   = (unsigned short*)alloc((size_t)M_ * D_ * 2);       // 16 MB
  unsigned short* Wcat = (unsigned short*)alloc((size_t)3 * D_ * D_ * 2);   // 6 MB
  unsigned short* Wot  = (unsigned short*)alloc((size_t)D_ * D_ * 2);       // 2 MB
  unsigned short* Qb   = (unsigned short*)alloc((size_t)B_ * H_ * S_ * DH_ * 2); // 16 MB
  unsigned short* Kb   = (unsigned short*)alloc((size_t)B_ * H_ * S_ * DH_ * 2); // 16 MB
  unsigned short* Vtb  = (unsigned short*)alloc((size_t)B_ * H_ * S_ * DH_ * 2); // 16 MB
  unsigned short* Cc   = (unsigned short*)alloc((size_t)M_ * D_ * 2);       // 16 MB

  cvt_x   <<<M_ * D_ / 4 / 256, 256, 0, stream>>>(x, xb);
  cvt_wqkv<<<3 * D_ * D_ / 256, 256, 0, stream>>>(Wq, Wk, Wv, Wcat);
  cvt_wo  <<<D_ * D_ / 256,     256, 0, stream>>>(Wo, Wot);
  gemm_qkv<<<dim3(3 * D_ / 128, M_ / 128), 256, 0, stream>>>(xb, Wcat, Qb, Kb, Vtb);
  flash_attn<<<dim3(S_ / 128, B_ * H_), 256, 0, stream>>>(Qb, Kb, Vtb, Cc);
  gemm_out<<<dim3(D_ / 128, M_ / 128), 256, 0, stream>>>(Cc, Wot, out);
}

// Round 4
// 376.733 us; speedup vs baseline: 1.1070x; 1.1070x over previous
//
#include <hip/hip_runtime.h>

// Problem constants
#define B_  4
#define S_  2048
#define D_  1024
#define H_  16
#define DH_ 64
#define M_  (B_*S_)   // 8192

typedef __bf16 bf8_t __attribute__((ext_vector_type(8)));
typedef float f4_t __attribute__((ext_vector_type(4)));
typedef unsigned short u16x8_t __attribute__((ext_vector_type(8)));

static __device__ __forceinline__ unsigned short f2bf(float f) {
  return __builtin_bit_cast(unsigned short, (__bf16)f);
}
static __device__ __forceinline__ bf8_t ldbf8(const unsigned short* p) {
  return __builtin_bit_cast(bf8_t, *(const u16x8_t*)p);
}
#define MFMA16(a,b,c) __builtin_amdgcn_mfma_f32_16x16x32_bf16((a),(b),(c),0,0,0)
#define GLDS16(gp, lp) __builtin_amdgcn_global_load_lds( \
    (const __attribute__((address_space(1))) void*)(gp), \
    (__attribute__((address_space(3))) void*)(lp), 16, 0, 0)

// 0.125 (1/sqrt(dh)) * log2(e): folded into Q so softmax uses bare exp2.
#define QSCALE 0.18033688011112042f

// ---------------- convert kernels ----------------

__global__ void cvt_x(const float* __restrict__ x, unsigned short* __restrict__ xb) {
  int i = blockIdx.x * 256 + threadIdx.x;            // over M_*D_/4
  float4 v = ((const float4*)x)[i];
  unsigned int lo = f2bf(v.x) | ((unsigned int)f2bf(v.y) << 16);
  unsigned int hi = f2bf(v.z) | ((unsigned int)f2bf(v.w) << 16);
  ((uint2*)xb)[i] = make_uint2(lo, hi);
}

// Wq/Wk/Wv are (H, D, DH). Build fused B^T weight: Wcat[n][k], n = qkv*1024 + h*64 + dh, k = d.
__global__ void cvt_wqkv(const float* __restrict__ Wq, const float* __restrict__ Wk,
                         const float* __restrict__ Wv, unsigned short* __restrict__ Wcat) {
  int i = blockIdx.x * 256 + threadIdx.x;            // over 3*1024*1024
  int qkv = i >> 20;
  int r   = i & ((1 << 20) - 1);
  int h   = r >> 16;
  int k   = (r & 65535) >> 6;
  int dh  = r & 63;
  const float* W = (qkv == 0) ? Wq : (qkv == 1 ? Wk : Wv);
  float v = W[r];                                    // r == h*65536 + k*64 + dh
  int n = qkv * 1024 + h * 64 + dh;
  Wcat[(size_t)n * 1024 + k] = f2bf(v);
}

// Wo is (D, D) row-major [d][n]. Build Wot[n][k=d].
__global__ void cvt_wo(const float* __restrict__ Wo, unsigned short* __restrict__ Wot) {
  int i = blockIdx.x * 256 + threadIdx.x;            // over 1024*1024
  int k = i >> 10, n = i & 1023;
  Wot[(size_t)n * 1024 + k] = f2bf(Wo[i]);
}

// ---------------- GEMM core (128x128 tile, BK=32, K=1024, B^T input) ----------------

static __device__ __forceinline__ void gemm_core(const unsigned short* __restrict__ A,
    const unsigned short* __restrict__ Bt, unsigned short* As, unsigned short* Bs,
    int bm, int bn, f4_t acc[4][4])
{
  const int tid = threadIdx.x, w = tid >> 6, lane = tid & 63;
  const int quad = lane >> 4, col = lane & 15;
  const int wm = (w >> 1) * 64, wn = (w & 1) * 64;
  const int srow = lane >> 2;                         // 0..15
  const int goff = (((lane & 3) ^ ((srow >> 1) & 3)) * 8);
  const unsigned short* ga = A  + (size_t)(bm + 32 * w + srow) * D_ + goff;
  const unsigned short* gb = Bt + (size_t)(bn + 32 * w + srow) * D_ + goff;
  unsigned short* lAs0 = &As[(32 * w) * 32];
  unsigned short* lAs1 = &As[(32 * w + 16) * 32];
  unsigned short* lBs0 = &Bs[(32 * w) * 32];
  unsigned short* lBs1 = &Bs[(32 * w + 16) * 32];
  const int psw = (quad ^ ((col >> 1) & 3)) * 8;

  for (int k0 = 0; k0 < D_; k0 += 32) {
    __syncthreads();
    GLDS16(ga + k0,           lAs0);
    GLDS16(ga + 16 * D_ + k0, lAs1);
    GLDS16(gb + k0,           lBs0);
    GLDS16(gb + 16 * D_ + k0, lBs1);
    __syncthreads();
    bf8_t af[4], bfv[4];
#pragma unroll
    for (int mt = 0; mt < 4; mt++) af[mt]  = ldbf8(&As[(wm + 16 * mt + col) * 32 + psw]);
#pragma unroll
    for (int nt = 0; nt < 4; nt++) bfv[nt] = ldbf8(&Bs[(wn + 16 * nt + col) * 32 + psw]);
#pragma unroll
    for (int mt = 0; mt < 4; mt++)
#pragma unroll
      for (int nt = 0; nt < 4; nt++)
        acc[mt][nt] = MFMA16(af[mt], bfv[nt], acc[mt][nt]);
  }
}

// ---------------- stage 1: QKV projection ----------------
// Q is pre-scaled by QSCALE (softmax scale folded in, exp2 base).

__global__ __launch_bounds__(256, 2) void gemm_qkv(const unsigned short* __restrict__ A,
    const unsigned short* __restrict__ Bt,
    unsigned short* __restrict__ Qp, unsigned short* __restrict__ Kp,
    unsigned short* __restrict__ Vtp)
{
  __shared__ __align__(16) unsigned short As[128 * 32];
  __shared__ __align__(16) unsigned short Bs[128 * 32];
  f4_t acc[4][4] = {};
  const int bm = blockIdx.y * 128, bn = blockIdx.x * 128;
  gemm_core(A, Bt, As, Bs, bm, bn, acc);

  const int tid = threadIdx.x, w = tid >> 6, lane = tid & 63;
  const int quad = lane >> 4, col = lane & 15;
  const int wm = (w >> 1) * 64, wn = (w & 1) * 64;
#pragma unroll
  for (int nt = 0; nt < 4; nt++) {
    int n = bn + wn + 16 * nt + col;
    int qkv = n >> 10, r1 = n & 1023, h = r1 >> 6, dh = r1 & 63;
#pragma unroll
    for (int mt = 0; mt < 4; mt++) {
      int m0 = bm + wm + 16 * mt + quad * 4;
      int b = m0 >> 11, s0 = m0 & 2047;
      if (qkv == 0) {
#pragma unroll
        for (int r = 0; r < 4; r++)
          Qp[((size_t)(b * H_ + h) * S_ + s0 + r) * DH_ + dh] = f2bf(acc[mt][nt][r] * QSCALE);
      } else if (qkv == 1) {
#pragma unroll
        for (int r = 0; r < 4; r++)
          Kp[((size_t)(b * H_ + h) * S_ + s0 + r) * DH_ + dh] = f2bf(acc[mt][nt][r]);
      } else {
        unsigned int lo = f2bf(acc[mt][nt][0]) | ((unsigned int)f2bf(acc[mt][nt][1]) << 16);
        unsigned int hi = f2bf(acc[mt][nt][2]) | ((unsigned int)f2bf(acc[mt][nt][3]) << 16);
        *(uint2*)&Vtp[((size_t)(b * H_ + h) * DH_ + dh) * S_ + s0] = make_uint2(lo, hi);
      }
    }
  }
}

// ---------------- stage 2: flash attention (no-max softmax, deferred l) ----------------
// Block = 128 Q-rows of one (b,h); wave w owns q-rows [32w,32w+32).
// Ks [sk][dh] (128x64, 16KB), Vs [dh][sk] (64x128, 16KB),
// Ps wave-private [32][64] (16KB total) -> 48KB LDS, 3 blocks/CU.
// kt body processes k-cols in two independent 64-wide halves so only
// sc[2][4] (32 VGPRs) is live at once -> no spill under the (256,3) cap.
// NOTE: V staging swizzle must include the per-instruction 4*j row term
// (vr & 15 = 4*j + (lane>>4)) — hoisting it j-independently broke R3.

__global__ __launch_bounds__(256, 3) void flash_attn(const unsigned short* __restrict__ Qp,
    const unsigned short* __restrict__ Kp, const unsigned short* __restrict__ Vtp,
    unsigned short* __restrict__ Cc)
{
  __shared__ __align__(16) unsigned short Ks[128 * 64];
  __shared__ __align__(16) unsigned short Vs[64 * 128];
  __shared__ __align__(16) unsigned short Ps[4][32 * 64];
  const int tid = threadIdx.x, w = tid >> 6, lane = tid & 63;
  const int quad = lane >> 4, col = lane & 15;
  const int qt = blockIdx.x, bh = blockIdx.y;

  // Q fragments straight from global (A-layout: row = lane&15, k contiguous); pre-scaled
  const unsigned short* Qg = Qp + ((size_t)bh * S_ + qt * 128 + w * 32) * DH_;
  bf8_t aq[2][2];
#pragma unroll
  for (int t = 0; t < 2; t++)
#pragma unroll
    for (int kc = 0; kc < 2; kc++)
      aq[t][kc] = ldbf8(Qg + (t * 16 + col) * DH_ + kc * 32 + quad * 8);

  f4_t o[2][4] = {};
  float lp[2][4] = {};                                // per-lane partial softmax sums

  const unsigned short* Kg0 = Kp  + (size_t)bh * S_ * DH_;
  const unsigned short* Vg0 = Vtp + (size_t)bh * DH_ * S_;
  unsigned short* Pw = &Ps[w][0];

  // K staging: j-independent hoist is safe (8*j ≡ 0 mod 8 in row & 7)
  const int krow_s = 32 * w + (lane >> 3);
  const int kgoff  = ((lane & 7) ^ (krow_s & 7)) * 8;
  const int vrow_r = lane >> 4;                       // 0..3

  for (int kt = 0; kt < S_ / 128; kt++) {
    __syncthreads();
    {
      const unsigned short* Kg = Kg0 + kt * 128 * DH_ + krow_s * DH_ + kgoff;
      const unsigned short* Vg = Vg0 + (size_t)(16 * w + vrow_r) * S_ + kt * 128;
#pragma unroll
      for (int j = 0; j < 4; j++)                         // K tile: 8 rows/instr
        GLDS16(Kg + 8 * j * DH_, &Ks[(32 * w + 8 * j) * 64]);
#pragma unroll
      for (int j = 0; j < 4; j++) {                       // V^T tile: 4 rows/instr
        int vgoff = (((lane & 15) ^ ((4 * j + vrow_r) & 15)) * 8);
        GLDS16(Vg + (size_t)(4 * j) * S_ + vgoff, &Vs[(16 * w + 4 * j) * 128]);
      }
    }
    __syncthreads();

    // two independent 64-col halves: QK^T -> exp2 -> P-store -> PV
#pragma unroll
    for (int hh = 0; hh < 2; hh++) {
      f4_t sc[2][4] = {};
#pragma unroll
      for (int ctl = 0; ctl < 4; ctl++) {
        int krow = (hh * 4 + ctl) * 16 + col;
#pragma unroll
        for (int kc = 0; kc < 2; kc++) {
          bf8_t bk = ldbf8(&Ks[krow * 64 + (((kc * 4 + quad) ^ (krow & 7)) * 8)]);
          sc[0][ctl] = MFMA16(aq[0][kc], bk, sc[0][ctl]);
          sc[1][ctl] = MFMA16(aq[1][kc], bk, sc[1][ctl]);
        }
      }

#pragma unroll
      for (int t = 0; t < 2; t++)
#pragma unroll
        for (int r = 0; r < 4; r++) {
          int rho = t * 16 + quad * 4 + r;
#pragma unroll
          for (int ctl = 0; ctl < 4; ctl++) {
            float p = __builtin_amdgcn_exp2f(sc[t][ctl][r]);
            lp[t][r] += p;
            int g = ctl * 2 + (col >> 3);
            Pw[rho * 64 + ((g ^ (rho & 7)) * 8) + (col & 7)] = f2bf(p);
          }
        }

#pragma unroll
      for (int kcl = 0; kcl < 2; kcl++) {
        bf8_t ap0 = ldbf8(&Pw[(0 * 16 + col) * 64 + (((kcl * 4 + quad) ^ (col & 7)) * 8)]);
        bf8_t ap1 = ldbf8(&Pw[(1 * 16 + col) * 64 + (((kcl * 4 + quad) ^ (col & 7)) * 8)]);
        int gk = hh * 8 + kcl * 4 + quad;
#pragma unroll
        for (int cv = 0; cv < 4; cv++) {
          int vr = cv * 16 + col;
          bf8_t bv = ldbf8(&Vs[vr * 128 + ((gk ^ col) * 8)]);
          o[0][cv] = MFMA16(ap0, bv, o[0][cv]);
          o[1][cv] = MFMA16(ap1, bv, o[1][cv]);
        }
      }
    }
  }

  // final l: reduce per-lane partials across the 16 col-lanes (once)
  float l[2][4];
#pragma unroll
  for (int t = 0; t < 2; t++)
#pragma unroll
    for (int r = 0; r < 4; r++) {
      float s = lp[t][r];
#pragma unroll
      for (int off = 1; off < 16; off <<= 1) s += __shfl_xor(s, off);
      l[t][r] = s;
    }

  // epilogue: O/l -> concat (b, s, h*64+dh) bf16
  const int b = bh >> 4, h = bh & 15;
#pragma unroll
  for (int t = 0; t < 2; t++)
#pragma unroll
    for (int cv = 0; cv < 4; cv++)
#pragma unroll
      for (int r = 0; r < 4; r++) {
        float v = o[t][cv][r] / l[t][r];
        int s = qt * 128 + w * 32 + t * 16 + quad * 4 + r;
        int dcol = h * 64 + cv * 16 + col;
        Cc[((size_t)b * S_ + s) * D_ + dcol] = f2bf(v);
      }
}

// ---------------- stage 3: output projection ----------------

__global__ __launch_bounds__(256, 2) void gemm_out(const unsigned short* __restrict__ A,
    const unsigned short* __restrict__ Bt, float* __restrict__ Out)
{
  __shared__ __align__(16) unsigned short As[128 * 32];
  __shared__ __align__(16) unsigned short Bs[128 * 32];
  f4_t acc[4][4] = {};
  const int bm = blockIdx.y * 128, bn = blockIdx.x * 128;
  gemm_core(A, Bt, As, Bs, bm, bn, acc);

  const int tid = threadIdx.x, w = tid >> 6, lane = tid & 63;
  const int quad = lane >> 4, col = lane & 15;
  const int wm = (w >> 1) * 64, wn = (w & 1) * 64;
#pragma unroll
  for (int nt = 0; nt < 4; nt++) {
    int n = bn + wn + 16 * nt + col;
#pragma unroll
    for (int mt = 0; mt < 4; mt++) {
      int m0 = bm + wm + 16 * mt + quad * 4;
#pragma unroll
      for (int r = 0; r < 4; r++)
        Out[(size_t)(m0 + r) * D_ + n] = acc[mt][nt][r];
    }
  }
}

// ---------------- launch ----------------

extern "C" void kernel_launch(void* const* d_in, const int* in_sizes, int n_in,
                              void* d_out, int out_size, void* d_ws, size_t ws_size,
                              hipStream_t stream) {
  const float* x  = (const float*)d_in[0];
  const float* Wq = (const float*)d_in[1];
  const float* Wk = (const float*)d_in[2];
  const float* Wv = (const float*)d_in[3];
  const float* Wo = (const float*)d_in[4];
  float* out = (float*)d_out;

  char* ws = (char*)d_ws;
  size_t off = 0;
  auto alloc = [&](size_t bytes) -> void* {
    void* p = ws + off;
    off += (bytes + 255) & ~(size_t)255;
    return p;
  };
  unsigned short* xb   = (unsigned short*)alloc((size_t)M_ * D_ * 2);       // 16 MB
  unsigned short* Wcat = (unsigned short*)alloc((size_t)3 * D_ * D_ * 2);   // 6 MB
  unsigned short* Wot  = (unsigned short*)alloc((size_t)D_ * D_ * 2);       // 2 MB
  unsigned short* Qb   = (unsigned short*)alloc((size_t)B_ * H_ * S_ * DH_ * 2); // 16 MB
  unsigned short* Kb   = (unsigned short*)alloc((size_t)B_ * H_ * S_ * DH_ * 2); // 16 MB
  unsigned short* Vtb  = (unsigned short*)alloc((size_t)B_ * H_ * S_ * DH_ * 2); // 16 MB
  unsigned short* Cc   = (unsigned short*)alloc((size_t)M_ * D_ * 2);       // 16 MB

  cvt_x   <<<M_ * D_ / 4 / 256, 256, 0, stream>>>(x, xb);
  cvt_wqkv<<<3 * D_ * D_ / 256, 256, 0, stream>>>(Wq, Wk, Wv, Wcat);
  cvt_wo  <<<D_ * D_ / 256,     256, 0, stream>>>(Wo, Wot);
  gemm_qkv<<<dim3(3 * D_ / 128, M_ / 128), 256, 0, stream>>>(xb, Wcat, Qb, Kb, Vtb);
  flash_attn<<<dim3(S_ / 128, B_ * H_), 256, 0, stream>>>(Qb, Kb, Vtb, Cc);
  gemm_out<<<dim3(D_ / 128, M_ / 128), 256, 0, stream>>>(Cc, Wot, out);
}

// Round 5
// 296.559 us; speedup vs baseline: 1.4063x; 1.2703x over previous
//
#include <hip/hip_runtime.h>

// Problem constants
#define B_  4
#define S_  2048
#define D_  1024
#define H_  16
#define DH_ 64
#define M_  (B_*S_)   // 8192

typedef __bf16 bf8_t __attribute__((ext_vector_type(8)));
typedef float f4_t __attribute__((ext_vector_type(4)));
typedef unsigned short u16x8_t __attribute__((ext_vector_type(8)));

static __device__ __forceinline__ unsigned short f2bf(float f) {
  return __builtin_bit_cast(unsigned short, (__bf16)f);
}
static __device__ __forceinline__ bf8_t ldbf8(const unsigned short* p) {
  return __builtin_bit_cast(bf8_t, *(const u16x8_t*)p);
}
#define MFMA16(a,b,c) __builtin_amdgcn_mfma_f32_16x16x32_bf16((a),(b),(c),0,0,0)
#define GLDS16(gp, lp) __builtin_amdgcn_global_load_lds( \
    (const __attribute__((address_space(1))) void*)(gp), \
    (__attribute__((address_space(3))) void*)(lp), 16, 0, 0)

// 0.125 (1/sqrt(dh)) * log2(e): folded into Q so softmax uses bare exp2.
#define QSCALE 0.18033688011112042f

// ---------------- fused convert kernel ----------------
// blocks [0,8192): x->bf16 ; [8192,20480): Wq/Wk/Wv -> fused B^T ; [20480,24576): Wo^T

__global__ void cvt_all(const float* __restrict__ x,
                        const float* __restrict__ Wq, const float* __restrict__ Wk,
                        const float* __restrict__ Wv, const float* __restrict__ Wo,
                        unsigned short* __restrict__ xb, unsigned short* __restrict__ Wcat,
                        unsigned short* __restrict__ Wot) {
  int blk = blockIdx.x;
  if (blk < 8192) {
    int i = blk * 256 + threadIdx.x;                 // over M_*D_/4
    float4 v = ((const float4*)x)[i];
    unsigned int lo = f2bf(v.x) | ((unsigned int)f2bf(v.y) << 16);
    unsigned int hi = f2bf(v.z) | ((unsigned int)f2bf(v.w) << 16);
    ((uint2*)xb)[i] = make_uint2(lo, hi);
  } else if (blk < 20480) {
    int i = (blk - 8192) * 256 + threadIdx.x;        // over 3*1024*1024
    int qkv = i >> 20;
    int r   = i & ((1 << 20) - 1);
    int h   = r >> 16;
    int k   = (r & 65535) >> 6;
    int dh  = r & 63;
    const float* W = (qkv == 0) ? Wq : (qkv == 1 ? Wk : Wv);
    float v = W[r];                                  // r == h*65536 + k*64 + dh
    int n = qkv * 1024 + h * 64 + dh;
    Wcat[(size_t)n * 1024 + k] = f2bf(v);
  } else {
    int i = (blk - 20480) * 256 + threadIdx.x;       // over 1024*1024
    int k = i >> 10, n = i & 1023;
    Wot[(size_t)n * 1024 + k] = f2bf(Wo[i]);
  }
}

// ---------------- GEMM core (128x128 tile, BK=32, K=1024, B^T input) ----------------

static __device__ __forceinline__ void gemm_core(const unsigned short* __restrict__ A,
    const unsigned short* __restrict__ Bt, unsigned short* As, unsigned short* Bs,
    int bm, int bn, f4_t acc[4][4])
{
  const int tid = threadIdx.x, w = tid >> 6, lane = tid & 63;
  const int quad = lane >> 4, col = lane & 15;
  const int wm = (w >> 1) * 64, wn = (w & 1) * 64;
  const int srow = lane >> 2;                         // 0..15
  const int goff = (((lane & 3) ^ ((srow >> 1) & 3)) * 8);
  const unsigned short* ga = A  + (size_t)(bm + 32 * w + srow) * D_ + goff;
  const unsigned short* gb = Bt + (size_t)(bn + 32 * w + srow) * D_ + goff;
  unsigned short* lAs0 = &As[(32 * w) * 32];
  unsigned short* lAs1 = &As[(32 * w + 16) * 32];
  unsigned short* lBs0 = &Bs[(32 * w) * 32];
  unsigned short* lBs1 = &Bs[(32 * w + 16) * 32];
  const int psw = (quad ^ ((col >> 1) & 3)) * 8;

  for (int k0 = 0; k0 < D_; k0 += 32) {
    __syncthreads();
    GLDS16(ga + k0,           lAs0);
    GLDS16(ga + 16 * D_ + k0, lAs1);
    GLDS16(gb + k0,           lBs0);
    GLDS16(gb + 16 * D_ + k0, lBs1);
    __syncthreads();
    bf8_t af[4], bfv[4];
#pragma unroll
    for (int mt = 0; mt < 4; mt++) af[mt]  = ldbf8(&As[(wm + 16 * mt + col) * 32 + psw]);
#pragma unroll
    for (int nt = 0; nt < 4; nt++) bfv[nt] = ldbf8(&Bs[(wn + 16 * nt + col) * 32 + psw]);
#pragma unroll
    for (int mt = 0; mt < 4; mt++)
#pragma unroll
      for (int nt = 0; nt < 4; nt++)
        acc[mt][nt] = MFMA16(af[mt], bfv[nt], acc[mt][nt]);
  }
}

// ---------------- stage 1: QKV projection ----------------
// Q is pre-scaled by QSCALE (softmax scale folded in, exp2 base).

__global__ __launch_bounds__(256, 2) void gemm_qkv(const unsigned short* __restrict__ A,
    const unsigned short* __restrict__ Bt,
    unsigned short* __restrict__ Qp, unsigned short* __restrict__ Kp,
    unsigned short* __restrict__ Vtp)
{
  __shared__ __align__(16) unsigned short As[128 * 32];
  __shared__ __align__(16) unsigned short Bs[128 * 32];
  f4_t acc[4][4] = {};
  const int bm = blockIdx.y * 128, bn = blockIdx.x * 128;
  gemm_core(A, Bt, As, Bs, bm, bn, acc);

  const int tid = threadIdx.x, w = tid >> 6, lane = tid & 63;
  const int quad = lane >> 4, col = lane & 15;
  const int wm = (w >> 1) * 64, wn = (w & 1) * 64;
#pragma unroll
  for (int nt = 0; nt < 4; nt++) {
    int n = bn + wn + 16 * nt + col;
    int qkv = n >> 10, r1 = n & 1023, h = r1 >> 6, dh = r1 & 63;
#pragma unroll
    for (int mt = 0; mt < 4; mt++) {
      int m0 = bm + wm + 16 * mt + quad * 4;
      int b = m0 >> 11, s0 = m0 & 2047;
      if (qkv == 0) {
#pragma unroll
        for (int r = 0; r < 4; r++)
          Qp[((size_t)(b * H_ + h) * S_ + s0 + r) * DH_ + dh] = f2bf(acc[mt][nt][r] * QSCALE);
      } else if (qkv == 1) {
#pragma unroll
        for (int r = 0; r < 4; r++)
          Kp[((size_t)(b * H_ + h) * S_ + s0 + r) * DH_ + dh] = f2bf(acc[mt][nt][r]);
      } else {
        unsigned int lo = f2bf(acc[mt][nt][0]) | ((unsigned int)f2bf(acc[mt][nt][1]) << 16);
        unsigned int hi = f2bf(acc[mt][nt][2]) | ((unsigned int)f2bf(acc[mt][nt][3]) << 16);
        *(uint2*)&Vtp[((size_t)(b * H_ + h) * DH_ + dh) * S_ + s0] = make_uint2(lo, hi);
      }
    }
  }
}

// ---------------- stage 2: flash attention, S^T formulation ----------------
// QK^T computed as S^T = MFMA(K_frag, Q_frag): C row = sk (r-contiguous!), col = q.
// -> P packs pairwise to bf16 and stores with 16 ds_write_b64/kt (was 64 b16),
//    landing directly in the PV A-operand layout Ps[q][sk] (b128 reads).
// Ks [sk][dh] 16KB, Vs [dh][sk] 16KB, Ps wave-private [32 q][64 sk] 16KB -> 48KB.
// l: per-lane (q = lane&15) accumulator, cross-quad reduce once at the end.
// NOTE (R3 bug): V staging swizzle must include the per-instruction 4*j row term.

__global__ __launch_bounds__(256, 3) void flash_attn(const unsigned short* __restrict__ Qp,
    const unsigned short* __restrict__ Kp, const unsigned short* __restrict__ Vtp,
    unsigned short* __restrict__ Cc)
{
  __shared__ __align__(16) unsigned short Ks[128 * 64];
  __shared__ __align__(16) unsigned short Vs[64 * 128];
  __shared__ __align__(16) unsigned short Ps[4][32 * 64];
  const int tid = threadIdx.x, w = tid >> 6, lane = tid & 63;
  const int quad = lane >> 4, col = lane & 15;
  const int qt = blockIdx.x, bh = blockIdx.y;

  // Q fragments straight from global (row = lane&15, k contiguous); pre-scaled.
  // Used as the B operand of the S^T MFMA (layout is identical either way).
  const unsigned short* Qg = Qp + ((size_t)bh * S_ + qt * 128 + w * 32) * DH_;
  bf8_t aq[2][2];
#pragma unroll
  for (int t = 0; t < 2; t++)
#pragma unroll
    for (int kc = 0; kc < 2; kc++)
      aq[t][kc] = ldbf8(Qg + (t * 16 + col) * DH_ + kc * 32 + quad * 8);

  f4_t o[2][4] = {};
  float lp[2] = {0.f, 0.f};                           // per-lane l partial for q = lane&15 (+16t)

  const unsigned short* Kg0 = Kp  + (size_t)bh * S_ * DH_;
  const unsigned short* Vg0 = Vtp + (size_t)bh * DH_ * S_;
  unsigned short* Pw = &Ps[w][0];

  // K staging: j-independent hoist is safe (8*j ≡ 0 mod 8 in row & 7)
  const int krow_s = 32 * w + (lane >> 3);
  const int kgoff  = ((lane & 7) ^ (krow_s & 7)) * 8;
  const int vrow_r = lane >> 4;                       // 0..3

  for (int kt = 0; kt < S_ / 128; kt++) {
    __syncthreads();
    {
      const unsigned short* Kg = Kg0 + kt * 128 * DH_ + krow_s * DH_ + kgoff;
      const unsigned short* Vg = Vg0 + (size_t)(16 * w + vrow_r) * S_ + kt * 128;
#pragma unroll
      for (int j = 0; j < 4; j++)                         // K tile: 8 rows/instr
        GLDS16(Kg + 8 * j * DH_, &Ks[(32 * w + 8 * j) * 64]);
#pragma unroll
      for (int j = 0; j < 4; j++) {                       // V^T tile: 4 rows/instr
        int vgoff = (((lane & 15) ^ ((4 * j + vrow_r) & 15)) * 8);
        GLDS16(Vg + (size_t)(4 * j) * S_ + vgoff, &Vs[(16 * w + 4 * j) * 128]);
      }
    }
    __syncthreads();

    // two independent 64-col halves: S^T -> exp2+pack -> P-store(b64) -> PV
#pragma unroll
    for (int hh = 0; hh < 2; hh++) {
      f4_t sc[2][4] = {};                               // S^T: row=sk_local, col=q
#pragma unroll
      for (int ctl = 0; ctl < 4; ctl++) {
        int krow = (hh * 4 + ctl) * 16 + col;
#pragma unroll
        for (int kc = 0; kc < 2; kc++) {
          bf8_t bk = ldbf8(&Ks[krow * 64 + (((kc * 4 + quad) ^ (krow & 7)) * 8)]);
          sc[0][ctl] = MFMA16(bk, aq[0][kc], sc[0][ctl]);   // note operand order: S^T
          sc[1][ctl] = MFMA16(bk, aq[1][kc], sc[1][ctl]);
        }
      }

      // exp2 + pairwise pack + b64 store into Ps[q][sk] (granule ^ (q&7) swizzle)
#pragma unroll
      for (int t = 0; t < 2; t++)
#pragma unroll
        for (int ctl = 0; ctl < 4; ctl++) {
          float p0 = __builtin_amdgcn_exp2f(sc[t][ctl][0]);
          float p1 = __builtin_amdgcn_exp2f(sc[t][ctl][1]);
          float p2 = __builtin_amdgcn_exp2f(sc[t][ctl][2]);
          float p3 = __builtin_amdgcn_exp2f(sc[t][ctl][3]);
          lp[t] += (p0 + p1) + (p2 + p3);
          unsigned int d0 = f2bf(p0) | ((unsigned int)f2bf(p1) << 16);
          unsigned int d1 = f2bf(p2) | ((unsigned int)f2bf(p3) << 16);
          int g = ctl * 2 + (quad >> 1);               // sk granule 0..7 within half
          unsigned short* dst = &Pw[(t * 16 + col) * 64 + ((g ^ (col & 7)) << 3) + (quad & 1) * 4];
          *(uint2*)dst = make_uint2(d0, d1);
        }

#pragma unroll
      for (int kcl = 0; kcl < 2; kcl++) {
        bf8_t ap0 = ldbf8(&Pw[(0 * 16 + col) * 64 + (((kcl * 4 + quad) ^ (col & 7)) << 3)]);
        bf8_t ap1 = ldbf8(&Pw[(1 * 16 + col) * 64 + (((kcl * 4 + quad) ^ (col & 7)) << 3)]);
        int gk = hh * 8 + kcl * 4 + quad;
#pragma unroll
        for (int cv = 0; cv < 4; cv++) {
          int vr = cv * 16 + col;
          bf8_t bv = ldbf8(&Vs[vr * 128 + ((gk ^ col) * 8)]);
          o[0][cv] = MFMA16(ap0, bv, o[0][cv]);
          o[1][cv] = MFMA16(ap1, bv, o[1][cv]);
        }
      }
    }
  }

  // final l: reduce across the 4 quads (lanes sharing lane&15), once
  float l[2];
#pragma unroll
  for (int t = 0; t < 2; t++) {
    float s = lp[t];
    s += __shfl_xor(s, 16);
    s += __shfl_xor(s, 32);
    l[t] = s;
  }

  // epilogue: O/l -> concat (b, s, h*64+dh) bf16.
  // o rows are q = quad*4+r (tile t); l lives at lane&15 == q -> redistribute by shuffle.
  const int b = bh >> 4, h = bh & 15;
#pragma unroll
  for (int t = 0; t < 2; t++) {
    float linv[4];
#pragma unroll
    for (int r = 0; r < 4; r++)
      linv[r] = 1.0f / __shfl(l[t], quad * 4 + r);
#pragma unroll
    for (int cv = 0; cv < 4; cv++)
#pragma unroll
      for (int r = 0; r < 4; r++) {
        float v = o[t][cv][r] * linv[r];
        int s = qt * 128 + w * 32 + t * 16 + quad * 4 + r;
        int dcol = h * 64 + cv * 16 + col;
        Cc[((size_t)b * S_ + s) * D_ + dcol] = f2bf(v);
      }
  }
}

// ---------------- stage 3: output projection ----------------

__global__ __launch_bounds__(256, 2) void gemm_out(const unsigned short* __restrict__ A,
    const unsigned short* __restrict__ Bt, float* __restrict__ Out)
{
  __shared__ __align__(16) unsigned short As[128 * 32];
  __shared__ __align__(16) unsigned short Bs[128 * 32];
  f4_t acc[4][4] = {};
  const int bm = blockIdx.y * 128, bn = blockIdx.x * 128;
  gemm_core(A, Bt, As, Bs, bm, bn, acc);

  const int tid = threadIdx.x, w = tid >> 6, lane = tid & 63;
  const int quad = lane >> 4, col = lane & 15;
  const int wm = (w >> 1) * 64, wn = (w & 1) * 64;
#pragma unroll
  for (int nt = 0; nt < 4; nt++) {
    int n = bn + wn + 16 * nt + col;
#pragma unroll
    for (int mt = 0; mt < 4; mt++) {
      int m0 = bm + wm + 16 * mt + quad * 4;
#pragma unroll
      for (int r = 0; r < 4; r++)
        Out[(size_t)(m0 + r) * D_ + n] = acc[mt][nt][r];
    }
  }
}

// ---------------- launch ----------------

extern "C" void kernel_launch(void* const* d_in, const int* in_sizes, int n_in,
                              void* d_out, int out_size, void* d_ws, size_t ws_size,
                              hipStream_t stream) {
  const float* x  = (const float*)d_in[0];
  const float* Wq = (const float*)d_in[1];
  const float* Wk = (const float*)d_in[2];
  const float* Wv = (const float*)d_in[3];
  const float* Wo = (const float*)d_in[4];
  float* out = (float*)d_out;

  char* ws = (char*)d_ws;
  size_t off = 0;
  auto alloc = [&](size_t bytes) -> void* {
    void* p = ws + off;
    off += (bytes + 255) & ~(size_t)255;
    return p;
  };
  unsigned short* xb   = (unsigned short*)alloc((size_t)M_ * D_ * 2);       // 16 MB
  unsigned short* Wcat = (unsigned short*)alloc((size_t)3 * D_ * D_ * 2);   // 6 MB
  unsigned short* Wot  = (unsigned short*)alloc((size_t)D_ * D_ * 2);       // 2 MB
  unsigned short* Qb   = (unsigned short*)alloc((size_t)B_ * H_ * S_ * DH_ * 2); // 16 MB
  unsigned short* Kb   = (unsigned short*)alloc((size_t)B_ * H_ * S_ * DH_ * 2); // 16 MB
  unsigned short* Vtb  = (unsigned short*)alloc((size_t)B_ * H_ * S_ * DH_ * 2); // 16 MB
  unsigned short* Cc   = (unsigned short*)alloc((size_t)M_ * D_ * 2);       // 16 MB

  cvt_all<<<24576, 256, 0, stream>>>(x, Wq, Wk, Wv, Wo, xb, Wcat, Wot);
  gemm_qkv<<<dim3(3 * D_ / 128, M_ / 128), 256, 0, stream>>>(xb, Wcat, Qb, Kb, Vtb);
  flash_attn<<<dim3(S_ / 128, B_ * H_), 256, 0, stream>>>(Qb, Kb, Vtb, Cc);
  gemm_out<<<dim3(D_ / 128, M_ / 128), 256, 0, stream>>>(Cc, Wot, out);
}

// Round 6
// 280.480 us; speedup vs baseline: 1.4869x; 1.0573x over previous
//
#include <hip/hip_runtime.h>

// Problem constants
#define B_  4
#define S_  2048
#define D_  1024
#define H_  16
#define DH_ 64
#define M_  (B_*S_)   // 8192

typedef __bf16 bf8_t __attribute__((ext_vector_type(8)));
typedef float f4_t __attribute__((ext_vector_type(4)));
typedef unsigned short u16x8_t __attribute__((ext_vector_type(8)));

static __device__ __forceinline__ unsigned short f2bf(float f) {
  return __builtin_bit_cast(unsigned short, (__bf16)f);
}
static __device__ __forceinline__ bf8_t ldbf8(const unsigned short* p) {
  return __builtin_bit_cast(bf8_t, *(const u16x8_t*)p);
}
#define MFMA16(a,b,c) __builtin_amdgcn_mfma_f32_16x16x32_bf16((a),(b),(c),0,0,0)
#define GLDS16(gp, lp) __builtin_amdgcn_global_load_lds( \
    (const __attribute__((address_space(1))) void*)(gp), \
    (__attribute__((address_space(3))) void*)(lp), 16, 0, 0)

// 0.125 (1/sqrt(dh)) * log2(e): folded into Q so softmax uses bare exp2.
#define QSCALE 0.18033688011112042f

// ---------------- fused convert kernel ----------------
// blocks [0,8192): x->bf16 (coalesced both sides)
// blocks [8192,8576): Wq/Wk/Wv -> Wcat^T via LDS tile (64dh x 128k per block)
// blocks [8576,8640): Wo -> Wot^T via LDS tile (128x128)

__global__ void cvt_all(const float* __restrict__ x,
                        const float* __restrict__ Wq, const float* __restrict__ Wk,
                        const float* __restrict__ Wv, const float* __restrict__ Wo,
                        unsigned short* __restrict__ xb, unsigned short* __restrict__ Wcat,
                        unsigned short* __restrict__ Wot) {
  __shared__ unsigned short T[128 * 130];             // 33.3 KB, used by transpose parts
  const int blk = blockIdx.x, tid = threadIdx.x;
  if (blk < 8192) {
    int i = blk * 256 + tid;                          // over M_*D_/4
    float4 v = ((const float4*)x)[i];
    unsigned int lo = f2bf(v.x) | ((unsigned int)f2bf(v.y) << 16);
    unsigned int hi = f2bf(v.z) | ((unsigned int)f2bf(v.w) << 16);
    ((uint2*)xb)[i] = make_uint2(lo, hi);
  } else if (blk < 8576) {
    // W (H,D,DH) slab: qkv/h from bid>>3, k-chunk 128 from bid&7.
    int bid = blk - 8192;
    int qh = bid >> 3, kc = bid & 7;
    int qkv = qh >> 4, h = qh & 15;
    const float* W = (qkv == 0) ? Wq : (qkv == 1 ? Wk : Wv);
    const float* src = W + (size_t)h * 65536 + (size_t)kc * 128 * 64;
    // load 128k x 64dh coalesced -> T[k][dh] (pad 66)
#pragma unroll
    for (int jj = 0; jj < 32; jj++) {
      int idx = jj * 256 + tid;                       // kl = idx>>6, dh = idx&63
      T[(idx >> 6) * 66 + (idx & 63)] = f2bf(src[idx]);
    }
    __syncthreads();
    // gather columns -> coalesced 16B writes: Wcat[n0+dh][kc*128 + k]
    int n0 = qkv * 1024 + h * 64;
#pragma unroll
    for (int it = 0; it < 4; it++) {
      int u = it * 256 + tid;                         // 0..1023
      int dh = u >> 4, k8 = (u & 15) * 8;
      unsigned short v[8];
#pragma unroll
      for (int ii = 0; ii < 8; ii++) v[ii] = T[(k8 + ii) * 66 + dh];
      *(u16x8_t*)&Wcat[(size_t)(n0 + dh) * 1024 + kc * 128 + k8] =
          *(const u16x8_t*)v;
    }
  } else {
    // Wo (D,D) row-major -> Wot[n][k]; 128x128 tile
    int bid = blk - 8576;
    int r0 = (bid >> 3) * 128, c0 = (bid & 7) * 128;  // r0: k-dim, c0: n-dim
#pragma unroll
    for (int jj = 0; jj < 64; jj++) {
      int idx = jj * 256 + tid;                       // i = idx>>7, j = idx&127
      int i = idx >> 7, j = idx & 127;
      T[i * 130 + j] = f2bf(Wo[(size_t)(r0 + i) * 1024 + c0 + j]);
    }
    __syncthreads();
#pragma unroll
    for (int it = 0; it < 8; it++) {
      int u = it * 256 + tid;                         // 0..2047
      int j = u >> 4, i8 = (u & 15) * 8;
      unsigned short v[8];
#pragma unroll
      for (int ii = 0; ii < 8; ii++) v[ii] = T[(i8 + ii) * 130 + j];
      *(u16x8_t*)&Wot[(size_t)(c0 + j) * 1024 + r0 + i8] = *(const u16x8_t*)v;
    }
  }
}

// ---------------- GEMM core (128x128 tile, BK=32, K=1024, B^T input) ----------------

static __device__ __forceinline__ void gemm_core(const unsigned short* __restrict__ A,
    const unsigned short* __restrict__ Bt, unsigned short* As, unsigned short* Bs,
    int bm, int bn, f4_t acc[4][4])
{
  const int tid = threadIdx.x, w = tid >> 6, lane = tid & 63;
  const int quad = lane >> 4, col = lane & 15;
  const int wm = (w >> 1) * 64, wn = (w & 1) * 64;
  const int srow = lane >> 2;                         // 0..15
  const int goff = (((lane & 3) ^ ((srow >> 1) & 3)) * 8);
  const unsigned short* ga = A  + (size_t)(bm + 32 * w + srow) * D_ + goff;
  const unsigned short* gb = Bt + (size_t)(bn + 32 * w + srow) * D_ + goff;
  unsigned short* lAs0 = &As[(32 * w) * 32];
  unsigned short* lAs1 = &As[(32 * w + 16) * 32];
  unsigned short* lBs0 = &Bs[(32 * w) * 32];
  unsigned short* lBs1 = &Bs[(32 * w + 16) * 32];
  const int psw = (quad ^ ((col >> 1) & 3)) * 8;

  for (int k0 = 0; k0 < D_; k0 += 32) {
    __syncthreads();
    GLDS16(ga + k0,           lAs0);
    GLDS16(ga + 16 * D_ + k0, lAs1);
    GLDS16(gb + k0,           lBs0);
    GLDS16(gb + 16 * D_ + k0, lBs1);
    __syncthreads();
    bf8_t af[4], bfv[4];
#pragma unroll
    for (int mt = 0; mt < 4; mt++) af[mt]  = ldbf8(&As[(wm + 16 * mt + col) * 32 + psw]);
#pragma unroll
    for (int nt = 0; nt < 4; nt++) bfv[nt] = ldbf8(&Bs[(wn + 16 * nt + col) * 32 + psw]);
#pragma unroll
    for (int mt = 0; mt < 4; mt++)
#pragma unroll
      for (int nt = 0; nt < 4; nt++)
        acc[mt][nt] = MFMA16(af[mt], bfv[nt], acc[mt][nt]);
  }
}

// ---------------- stage 1: QKV projection ----------------
// qkv type is uniform per block (bn strip of 128). Q/K epilogue goes through a
// 32x128 LDS tile (4 passes) -> fully coalesced 16B/lane stores. V keeps the
// direct 8B s-contiguous store (already r-contiguous).

__global__ __launch_bounds__(256, 2) void gemm_qkv(const unsigned short* __restrict__ A,
    const unsigned short* __restrict__ Bt,
    unsigned short* __restrict__ Qp, unsigned short* __restrict__ Kp,
    unsigned short* __restrict__ Vtp)
{
  __shared__ __align__(16) unsigned short As[128 * 32];
  __shared__ __align__(16) unsigned short Bs[128 * 32];
  __shared__ __align__(16) unsigned short Cs[32 * 136];   // 8.7 KB epilogue tile
  f4_t acc[4][4] = {};
  const int bm = blockIdx.y * 128, bn = blockIdx.x * 128;
  gemm_core(A, Bt, As, Bs, bm, bn, acc);

  const int tid = threadIdx.x, w = tid >> 6, lane = tid & 63;
  const int quad = lane >> 4, col = lane & 15;
  const int wn = (w & 1) * 64;
  const int qkv = bn >> 10;

  if (qkv == 2) {
    const int wm = (w >> 1) * 64;
#pragma unroll
    for (int nt = 0; nt < 4; nt++) {
      int n = bn + wn + 16 * nt + col;
      int r1 = n & 1023, h = r1 >> 6, dh = r1 & 63;
#pragma unroll
      for (int mt = 0; mt < 4; mt++) {
        int m0 = bm + wm + 16 * mt + quad * 4;
        int b = m0 >> 11, s0 = m0 & 2047;
        unsigned int lo = f2bf(acc[mt][nt][0]) | ((unsigned int)f2bf(acc[mt][nt][1]) << 16);
        unsigned int hi = f2bf(acc[mt][nt][2]) | ((unsigned int)f2bf(acc[mt][nt][3]) << 16);
        *(uint2*)&Vtp[((size_t)(b * H_ + h) * DH_ + dh) * S_ + s0] = make_uint2(lo, hi);
      }
    }
    return;
  }

  const float qs = (qkv == 0) ? QSCALE : 1.0f;
  unsigned short* dst = (qkv == 0) ? Qp : Kp;
  const int h0 = (bn & 1023) >> 6;                    // this strip covers heads h0, h0+1
#pragma unroll
  for (int p = 0; p < 4; p++) {
    __syncthreads();
    if ((w >> 1) == (p >> 1)) {                       // 2 waves store rows [32p,32p+32)
#pragma unroll
      for (int mi = 0; mi < 2; mi++) {
        int mt = 2 * (p & 1) + mi;
        int lr0 = mi * 16 + quad * 4;
#pragma unroll
        for (int nt = 0; nt < 4; nt++) {
          int n = wn + nt * 16 + col;
#pragma unroll
          for (int r = 0; r < 4; r++)
            Cs[(lr0 + r) * 136 + n] = f2bf(acc[mt][nt][r] * qs);
        }
      }
    }
    __syncthreads();
#pragma unroll
    for (int it = 0; it < 2; it++) {
      int u = it * 256 + tid;                         // 0..511
      int lr = u >> 4, kk8 = u & 15;
      u16x8_t v = *(const u16x8_t*)&Cs[lr * 136 + kk8 * 8];
      int g = bm + 32 * p + lr;
      int b = g >> 11, s = g & 2047;
      int h = h0 + (kk8 >> 3), dh0 = (kk8 & 7) * 8;
      *(u16x8_t*)&dst[((size_t)(b * H_ + h) * S_ + s) * DH_ + dh0] = v;
    }
  }
}

// ---------------- stage 2: flash attention, S^T formulation ----------------
// grid(bh, qt): all 16 q-tiles of a head share blockIdx.x%8 -> same XCD ->
// K/V re-reads served by that XCD's L2 (8 heads x 512KB = 4MB = L2 size).
// QK^T computed as S^T = MFMA(K_frag, Q_frag): C row = sk (r-contiguous), col = q.
// P packs pairwise to bf16, 16 ds_write_b64/kt, directly in PV A-layout Ps[q][sk].
// Ks 16KB, Vs 16KB, Ps 16KB -> 48KB LDS, 3 blocks/CU.
// NOTE (R3 bug): V staging swizzle must include the per-instruction 4*j row term.

__global__ __launch_bounds__(256, 3) void flash_attn(const unsigned short* __restrict__ Qp,
    const unsigned short* __restrict__ Kp, const unsigned short* __restrict__ Vtp,
    unsigned short* __restrict__ Cc)
{
  __shared__ __align__(16) unsigned short Ks[128 * 64];
  __shared__ __align__(16) unsigned short Vs[64 * 128];
  __shared__ __align__(16) unsigned short Ps[4][32 * 64];
  const int tid = threadIdx.x, w = tid >> 6, lane = tid & 63;
  const int quad = lane >> 4, col = lane & 15;
  const int bh = blockIdx.x, qt = blockIdx.y;

  // Q fragments straight from global (row = lane&15, k contiguous); pre-scaled.
  const unsigned short* Qg = Qp + ((size_t)bh * S_ + qt * 128 + w * 32) * DH_;
  bf8_t aq[2][2];
#pragma unroll
  for (int t = 0; t < 2; t++)
#pragma unroll
    for (int kc = 0; kc < 2; kc++)
      aq[t][kc] = ldbf8(Qg + (t * 16 + col) * DH_ + kc * 32 + quad * 8);

  f4_t o[2][4] = {};
  float lp[2] = {0.f, 0.f};                           // per-lane l partial for q = lane&15 (+16t)

  const unsigned short* Kg0 = Kp  + (size_t)bh * S_ * DH_;
  const unsigned short* Vg0 = Vtp + (size_t)bh * DH_ * S_;
  unsigned short* Pw = &Ps[w][0];

  // K staging: j-independent hoist is safe (8*j ≡ 0 mod 8 in row & 7)
  const int krow_s = 32 * w + (lane >> 3);
  const int kgoff  = ((lane & 7) ^ (krow_s & 7)) * 8;
  const int vrow_r = lane >> 4;                       // 0..3

  for (int kt = 0; kt < S_ / 128; kt++) {
    __syncthreads();
    {
      const unsigned short* Kg = Kg0 + kt * 128 * DH_ + krow_s * DH_ + kgoff;
      const unsigned short* Vg = Vg0 + (size_t)(16 * w + vrow_r) * S_ + kt * 128;
#pragma unroll
      for (int j = 0; j < 4; j++)                         // K tile: 8 rows/instr
        GLDS16(Kg + 8 * j * DH_, &Ks[(32 * w + 8 * j) * 64]);
#pragma unroll
      for (int j = 0; j < 4; j++) {                       // V^T tile: 4 rows/instr
        int vgoff = (((lane & 15) ^ ((4 * j + vrow_r) & 15)) * 8);
        GLDS16(Vg + (size_t)(4 * j) * S_ + vgoff, &Vs[(16 * w + 4 * j) * 128]);
      }
    }
    __syncthreads();

    // two independent 64-col halves: S^T -> exp2+pack -> P-store(b64) -> PV
#pragma unroll
    for (int hh = 0; hh < 2; hh++) {
      f4_t sc[2][4] = {};                               // S^T: row=sk_local, col=q
#pragma unroll
      for (int ctl = 0; ctl < 4; ctl++) {
        int krow = (hh * 4 + ctl) * 16 + col;
#pragma unroll
        for (int kc = 0; kc < 2; kc++) {
          bf8_t bk = ldbf8(&Ks[krow * 64 + (((kc * 4 + quad) ^ (krow & 7)) * 8)]);
          sc[0][ctl] = MFMA16(bk, aq[0][kc], sc[0][ctl]);   // operand order: S^T
          sc[1][ctl] = MFMA16(bk, aq[1][kc], sc[1][ctl]);
        }
      }

      // exp2 + pairwise pack + b64 store into Ps[q][sk] (granule ^ (q&7) swizzle)
#pragma unroll
      for (int t = 0; t < 2; t++)
#pragma unroll
        for (int ctl = 0; ctl < 4; ctl++) {
          float p0 = __builtin_amdgcn_exp2f(sc[t][ctl][0]);
          float p1 = __builtin_amdgcn_exp2f(sc[t][ctl][1]);
          float p2 = __builtin_amdgcn_exp2f(sc[t][ctl][2]);
          float p3 = __builtin_amdgcn_exp2f(sc[t][ctl][3]);
          lp[t] += (p0 + p1) + (p2 + p3);
          unsigned int d0 = f2bf(p0) | ((unsigned int)f2bf(p1) << 16);
          unsigned int d1 = f2bf(p2) | ((unsigned int)f2bf(p3) << 16);
          int g = ctl * 2 + (quad >> 1);               // sk granule 0..7 within half
          unsigned short* pdst = &Pw[(t * 16 + col) * 64 + ((g ^ (col & 7)) << 3) + (quad & 1) * 4];
          *(uint2*)pdst = make_uint2(d0, d1);
        }

#pragma unroll
      for (int kcl = 0; kcl < 2; kcl++) {
        bf8_t ap0 = ldbf8(&Pw[(0 * 16 + col) * 64 + (((kcl * 4 + quad) ^ (col & 7)) << 3)]);
        bf8_t ap1 = ldbf8(&Pw[(1 * 16 + col) * 64 + (((kcl * 4 + quad) ^ (col & 7)) << 3)]);
        int gk = hh * 8 + kcl * 4 + quad;
#pragma unroll
        for (int cv = 0; cv < 4; cv++) {
          int vr = cv * 16 + col;
          bf8_t bv = ldbf8(&Vs[vr * 128 + ((gk ^ col) * 8)]);
          o[0][cv] = MFMA16(ap0, bv, o[0][cv]);
          o[1][cv] = MFMA16(ap1, bv, o[1][cv]);
        }
      }
    }
  }

  // final l: reduce across the 4 quads (lanes sharing lane&15), once
  float l[2];
#pragma unroll
  for (int t = 0; t < 2; t++) {
    float s = lp[t];
    s += __shfl_xor(s, 16);
    s += __shfl_xor(s, 32);
    l[t] = s;
  }

  // epilogue: O/l -> concat (b, s, h*64+dh) bf16; l redistributed by shuffle.
  const int b = bh >> 4, h = bh & 15;
#pragma unroll
  for (int t = 0; t < 2; t++) {
    float linv[4];
#pragma unroll
    for (int r = 0; r < 4; r++)
      linv[r] = 1.0f / __shfl(l[t], quad * 4 + r);
#pragma unroll
    for (int cv = 0; cv < 4; cv++)
#pragma unroll
      for (int r = 0; r < 4; r++) {
        float v = o[t][cv][r] * linv[r];
        int s = qt * 128 + w * 32 + t * 16 + quad * 4 + r;
        int dcol = h * 64 + cv * 16 + col;
        Cc[((size_t)b * S_ + s) * D_ + dcol] = f2bf(v);
      }
  }
}

// ---------------- stage 3: output projection ----------------
// f32 epilogue via 32x128 LDS tile -> 16B/lane coalesced stores.

__global__ __launch_bounds__(256, 2) void gemm_out(const unsigned short* __restrict__ A,
    const unsigned short* __restrict__ Bt, float* __restrict__ Out)
{
  __shared__ __align__(16) unsigned short As[128 * 32];
  __shared__ __align__(16) unsigned short Bs[128 * 32];
  __shared__ __align__(16) float Cf[32 * 132];            // 16.9 KB epilogue tile
  f4_t acc[4][4] = {};
  const int bm = blockIdx.y * 128, bn = blockIdx.x * 128;
  gemm_core(A, Bt, As, Bs, bm, bn, acc);

  const int tid = threadIdx.x, w = tid >> 6, lane = tid & 63;
  const int quad = lane >> 4, col = lane & 15;
  const int wn = (w & 1) * 64;
#pragma unroll
  for (int p = 0; p < 4; p++) {
    __syncthreads();
    if ((w >> 1) == (p >> 1)) {
#pragma unroll
      for (int mi = 0; mi < 2; mi++) {
        int mt = 2 * (p & 1) + mi;
        int lr0 = mi * 16 + quad * 4;
#pragma unroll
        for (int nt = 0; nt < 4; nt++) {
          int n = wn + nt * 16 + col;
#pragma unroll
          for (int r = 0; r < 4; r++)
            Cf[(lr0 + r) * 132 + n] = acc[mt][nt][r];
        }
      }
    }
    __syncthreads();
#pragma unroll
    for (int it = 0; it < 4; it++) {
      int u = it * 256 + tid;                         // 0..1023
      int lr = u >> 5, kk4 = u & 31;
      f4_t v = *(const f4_t*)&Cf[lr * 132 + kk4 * 4];
      int g = bm + 32 * p + lr;
      *(f4_t*)&Out[(size_t)g * D_ + bn + kk4 * 4] = v;
    }
  }
}

// ---------------- launch ----------------

extern "C" void kernel_launch(void* const* d_in, const int* in_sizes, int n_in,
                              void* d_out, int out_size, void* d_ws, size_t ws_size,
                              hipStream_t stream) {
  const float* x  = (const float*)d_in[0];
  const float* Wq = (const float*)d_in[1];
  const float* Wk = (const float*)d_in[2];
  const float* Wv = (const float*)d_in[3];
  const float* Wo = (const float*)d_in[4];
  float* out = (float*)d_out;

  char* ws = (char*)d_ws;
  size_t off = 0;
  auto alloc = [&](size_t bytes) -> void* {
    void* p = ws + off;
    off += (bytes + 255) & ~(size_t)255;
    return p;
  };
  unsigned short* xb   = (unsigned short*)alloc((size_t)M_ * D_ * 2);       // 16 MB
  unsigned short* Wcat = (unsigned short*)alloc((size_t)3 * D_ * D_ * 2);   // 6 MB
  unsigned short* Wot  = (unsigned short*)alloc((size_t)D_ * D_ * 2);       // 2 MB
  unsigned short* Qb   = (unsigned short*)alloc((size_t)B_ * H_ * S_ * DH_ * 2); // 16 MB
  unsigned short* Kb   = (unsigned short*)alloc((size_t)B_ * H_ * S_ * DH_ * 2); // 16 MB
  unsigned short* Vtb  = (unsigned short*)alloc((size_t)B_ * H_ * S_ * DH_ * 2); // 16 MB
  unsigned short* Cc   = (unsigned short*)alloc((size_t)M_ * D_ * 2);       // 16 MB

  cvt_all<<<8640, 256, 0, stream>>>(x, Wq, Wk, Wv, Wo, xb, Wcat, Wot);
  gemm_qkv<<<dim3(3 * D_ / 128, M_ / 128), 256, 0, stream>>>(xb, Wcat, Qb, Kb, Vtb);
  flash_attn<<<dim3(B_ * H_, S_ / 128), 256, 0, stream>>>(Qb, Kb, Vtb, Cc);
  gemm_out<<<dim3(D_ / 128, M_ / 128), 256, 0, stream>>>(Cc, Wot, out);
}

// Round 7
// 271.875 us; speedup vs baseline: 1.5340x; 1.0317x over previous
//
#include <hip/hip_runtime.h>

// Problem constants
#define B_  4
#define S_  2048
#define D_  1024
#define H_  16
#define DH_ 64
#define M_  (B_*S_)   // 8192

typedef __bf16 bf8_t __attribute__((ext_vector_type(8)));
typedef float f4_t __attribute__((ext_vector_type(4)));
typedef unsigned short u16x8_t __attribute__((ext_vector_type(8)));

static __device__ __forceinline__ unsigned short f2bf(float f) {
  return __builtin_bit_cast(unsigned short, (__bf16)f);
}
static __device__ __forceinline__ bf8_t ldbf8(const unsigned short* p) {
  return __builtin_bit_cast(bf8_t, *(const u16x8_t*)p);
}
// pack two positive f32 -> (bf16(b)<<16)|bf16(a), round-half-up, 3 VALU ops
static __device__ __forceinline__ unsigned int pkbf(float a, float b) {
  unsigned int ua = __builtin_bit_cast(unsigned int, a) + 0x8000u;
  unsigned int ub = __builtin_bit_cast(unsigned int, b) + 0x8000u;
  return __builtin_amdgcn_perm(ub, ua, 0x07060302);
}
#define MFMA16(a,b,c) __builtin_amdgcn_mfma_f32_16x16x32_bf16((a),(b),(c),0,0,0)
#define GLDS16(gp, lp) __builtin_amdgcn_global_load_lds( \
    (const __attribute__((address_space(1))) void*)(gp), \
    (__attribute__((address_space(3))) void*)(lp), 16, 0, 0)

// 0.125 (1/sqrt(dh)) * log2(e): folded into Q so softmax uses bare exp2.
#define QSCALE 0.18033688011112042f

// ---------------- fused convert kernel ----------------
// blocks [0,8192): x->bf16 (coalesced both sides)
// blocks [8192,8576): Wq/Wk/Wv -> Wcat^T via LDS tile (64dh x 128k per block)
// blocks [8576,8640): Wo -> Wot^T via LDS tile (128x128)

__global__ void cvt_all(const float* __restrict__ x,
                        const float* __restrict__ Wq, const float* __restrict__ Wk,
                        const float* __restrict__ Wv, const float* __restrict__ Wo,
                        unsigned short* __restrict__ xb, unsigned short* __restrict__ Wcat,
                        unsigned short* __restrict__ Wot) {
  __shared__ unsigned short T[128 * 130];             // 33.3 KB, used by transpose parts
  const int blk = blockIdx.x, tid = threadIdx.x;
  if (blk < 8192) {
    int i = blk * 256 + tid;                          // over M_*D_/4
    float4 v = ((const float4*)x)[i];
    unsigned int lo = f2bf(v.x) | ((unsigned int)f2bf(v.y) << 16);
    unsigned int hi = f2bf(v.z) | ((unsigned int)f2bf(v.w) << 16);
    ((uint2*)xb)[i] = make_uint2(lo, hi);
  } else if (blk < 8576) {
    // W (H,D,DH) slab: qkv/h from bid>>3, k-chunk 128 from bid&7.
    int bid = blk - 8192;
    int qh = bid >> 3, kc = bid & 7;
    int qkv = qh >> 4, h = qh & 15;
    const float* W = (qkv == 0) ? Wq : (qkv == 1 ? Wk : Wv);
    const float* src = W + (size_t)h * 65536 + (size_t)kc * 128 * 64;
    // load 128k x 64dh coalesced -> T[k][dh] (pad 66)
#pragma unroll
    for (int jj = 0; jj < 32; jj++) {
      int idx = jj * 256 + tid;                       // kl = idx>>6, dh = idx&63
      T[(idx >> 6) * 66 + (idx & 63)] = f2bf(src[idx]);
    }
    __syncthreads();
    // gather columns -> coalesced 16B writes: Wcat[n0+dh][kc*128 + k]
    int n0 = qkv * 1024 + h * 64;
#pragma unroll
    for (int it = 0; it < 4; it++) {
      int u = it * 256 + tid;                         // 0..1023
      int dh = u >> 4, k8 = (u & 15) * 8;
      unsigned short v[8];
#pragma unroll
      for (int ii = 0; ii < 8; ii++) v[ii] = T[(k8 + ii) * 66 + dh];
      *(u16x8_t*)&Wcat[(size_t)(n0 + dh) * 1024 + kc * 128 + k8] =
          *(const u16x8_t*)v;
    }
  } else {
    // Wo (D,D) row-major -> Wot[n][k]; 128x128 tile
    int bid = blk - 8576;
    int r0 = (bid >> 3) * 128, c0 = (bid & 7) * 128;  // r0: k-dim, c0: n-dim
#pragma unroll
    for (int jj = 0; jj < 64; jj++) {
      int idx = jj * 256 + tid;                       // i = idx>>7, j = idx&127
      int i = idx >> 7, j = idx & 127;
      T[i * 130 + j] = f2bf(Wo[(size_t)(r0 + i) * 1024 + c0 + j]);
    }
    __syncthreads();
#pragma unroll
    for (int it = 0; it < 8; it++) {
      int u = it * 256 + tid;                         // 0..2047
      int j = u >> 4, i8 = (u & 15) * 8;
      unsigned short v[8];
#pragma unroll
      for (int ii = 0; ii < 8; ii++) v[ii] = T[(i8 + ii) * 130 + j];
      *(u16x8_t*)&Wot[(size_t)(c0 + j) * 1024 + r0 + i8] = *(const u16x8_t*)v;
    }
  }
}

// ---------------- GEMM core (128x128 tile, BK=32, K=1024, B^T input) ----------------

static __device__ __forceinline__ void gemm_core(const unsigned short* __restrict__ A,
    const unsigned short* __restrict__ Bt, unsigned short* As, unsigned short* Bs,
    int bm, int bn, f4_t acc[4][4])
{
  const int tid = threadIdx.x, w = tid >> 6, lane = tid & 63;
  const int quad = lane >> 4, col = lane & 15;
  const int wm = (w >> 1) * 64, wn = (w & 1) * 64;
  const int srow = lane >> 2;                         // 0..15
  const int goff = (((lane & 3) ^ ((srow >> 1) & 3)) * 8);
  const unsigned short* ga = A  + (size_t)(bm + 32 * w + srow) * D_ + goff;
  const unsigned short* gb = Bt + (size_t)(bn + 32 * w + srow) * D_ + goff;
  unsigned short* lAs0 = &As[(32 * w) * 32];
  unsigned short* lAs1 = &As[(32 * w + 16) * 32];
  unsigned short* lBs0 = &Bs[(32 * w) * 32];
  unsigned short* lBs1 = &Bs[(32 * w + 16) * 32];
  const int psw = (quad ^ ((col >> 1) & 3)) * 8;

  for (int k0 = 0; k0 < D_; k0 += 32) {
    __syncthreads();
    GLDS16(ga + k0,           lAs0);
    GLDS16(ga + 16 * D_ + k0, lAs1);
    GLDS16(gb + k0,           lBs0);
    GLDS16(gb + 16 * D_ + k0, lBs1);
    __syncthreads();
    bf8_t af[4], bfv[4];
#pragma unroll
    for (int mt = 0; mt < 4; mt++) af[mt]  = ldbf8(&As[(wm + 16 * mt + col) * 32 + psw]);
#pragma unroll
    for (int nt = 0; nt < 4; nt++) bfv[nt] = ldbf8(&Bs[(wn + 16 * nt + col) * 32 + psw]);
#pragma unroll
    for (int mt = 0; mt < 4; mt++)
#pragma unroll
      for (int nt = 0; nt < 4; nt++)
        acc[mt][nt] = MFMA16(af[mt], bfv[nt], acc[mt][nt]);
  }
}

// ---------------- stage 1: QKV projection ----------------
// qkv type is uniform per block (bn strip of 128). Q/K epilogue goes through a
// 32x128 LDS tile (4 passes) -> fully coalesced 16B/lane stores. V keeps the
// direct 8B s-contiguous store (already r-contiguous).

__global__ __launch_bounds__(256, 2) void gemm_qkv(const unsigned short* __restrict__ A,
    const unsigned short* __restrict__ Bt,
    unsigned short* __restrict__ Qp, unsigned short* __restrict__ Kp,
    unsigned short* __restrict__ Vtp)
{
  __shared__ __align__(16) unsigned short As[128 * 32];
  __shared__ __align__(16) unsigned short Bs[128 * 32];
  __shared__ __align__(16) unsigned short Cs[32 * 136];   // 8.7 KB epilogue tile
  f4_t acc[4][4] = {};
  const int bm = blockIdx.y * 128, bn = blockIdx.x * 128;
  gemm_core(A, Bt, As, Bs, bm, bn, acc);

  const int tid = threadIdx.x, w = tid >> 6, lane = tid & 63;
  const int quad = lane >> 4, col = lane & 15;
  const int wn = (w & 1) * 64;
  const int qkv = bn >> 10;

  if (qkv == 2) {
    const int wm = (w >> 1) * 64;
#pragma unroll
    for (int nt = 0; nt < 4; nt++) {
      int n = bn + wn + 16 * nt + col;
      int r1 = n & 1023, h = r1 >> 6, dh = r1 & 63;
#pragma unroll
      for (int mt = 0; mt < 4; mt++) {
        int m0 = bm + wm + 16 * mt + quad * 4;
        int b = m0 >> 11, s0 = m0 & 2047;
        unsigned int lo = f2bf(acc[mt][nt][0]) | ((unsigned int)f2bf(acc[mt][nt][1]) << 16);
        unsigned int hi = f2bf(acc[mt][nt][2]) | ((unsigned int)f2bf(acc[mt][nt][3]) << 16);
        *(uint2*)&Vtp[((size_t)(b * H_ + h) * DH_ + dh) * S_ + s0] = make_uint2(lo, hi);
      }
    }
    return;
  }

  const float qs = (qkv == 0) ? QSCALE : 1.0f;
  unsigned short* dst = (qkv == 0) ? Qp : Kp;
  const int h0 = (bn & 1023) >> 6;                    // this strip covers heads h0, h0+1
#pragma unroll
  for (int p = 0; p < 4; p++) {
    __syncthreads();
    if ((w >> 1) == (p >> 1)) {                       // 2 waves store rows [32p,32p+32)
#pragma unroll
      for (int mi = 0; mi < 2; mi++) {
        int mt = 2 * (p & 1) + mi;
        int lr0 = mi * 16 + quad * 4;
#pragma unroll
        for (int nt = 0; nt < 4; nt++) {
          int n = wn + nt * 16 + col;
#pragma unroll
          for (int r = 0; r < 4; r++)
            Cs[(lr0 + r) * 136 + n] = f2bf(acc[mt][nt][r] * qs);
        }
      }
    }
    __syncthreads();
#pragma unroll
    for (int it = 0; it < 2; it++) {
      int u = it * 256 + tid;                         // 0..511
      int lr = u >> 4, kk8 = u & 15;
      u16x8_t v = *(const u16x8_t*)&Cs[lr * 136 + kk8 * 8];
      int g = bm + 32 * p + lr;
      int b = g >> 11, s = g & 2047;
      int h = h0 + (kk8 >> 3), dh0 = (kk8 & 7) * 8;
      *(u16x8_t*)&dst[((size_t)(b * H_ + h) * S_ + s) * DH_ + dh0] = v;
    }
  }
}

// ---------------- stage 2: flash attention, S^T formulation ----------------
// grid(bh, qt): all 16 q-tiles of a head share blockIdx.x%8 -> same XCD L2.
// S^T = MFMA(K_frag, Q_frag): C row = sk (r-contiguous), col = q.
// P packs via add+v_perm (3 VALU/pair), 16 ds_write_b64/kt, PV A-layout Ps[q][sk].
// l accumulated by MFMA with an all-ones B operand (lands in o's C-row layout,
// no shuffles, and equals the sum of the *quantized* P used in PV).
// Ks 16KB, Vs 16KB, Ps 16KB -> 48KB LDS, 3 blocks/CU.
// NOTE (R3 bug): V staging swizzle must include the per-instruction 4*j row term.

__global__ __launch_bounds__(256, 3) void flash_attn(const unsigned short* __restrict__ Qp,
    const unsigned short* __restrict__ Kp, const unsigned short* __restrict__ Vtp,
    unsigned short* __restrict__ Cc)
{
  __shared__ __align__(16) unsigned short Ks[128 * 64];
  __shared__ __align__(16) unsigned short Vs[64 * 128];
  __shared__ __align__(16) unsigned short Ps[4][32 * 64];
  const int tid = threadIdx.x, w = tid >> 6, lane = tid & 63;
  const int quad = lane >> 4, col = lane & 15;
  const int bh = blockIdx.x, qt = blockIdx.y;

  // Q fragments straight from global (row = lane&15, k contiguous); pre-scaled.
  const unsigned short* Qg = Qp + ((size_t)bh * S_ + qt * 128 + w * 32) * DH_;
  bf8_t aq[2][2];
#pragma unroll
  for (int t = 0; t < 2; t++)
#pragma unroll
    for (int kc = 0; kc < 2; kc++)
      aq[t][kc] = ldbf8(Qg + (t * 16 + col) * DH_ + kc * 32 + quad * 8);

  const bf8_t vones = __builtin_bit_cast(bf8_t, (u16x8_t)((unsigned short)0x3F80));
  f4_t o[2][4] = {};
  f4_t lacc[2] = {};                                  // l in o-row layout via ones-MFMA

  const unsigned short* Kg0 = Kp  + (size_t)bh * S_ * DH_;
  const unsigned short* Vg0 = Vtp + (size_t)bh * DH_ * S_;
  unsigned short* Pw = &Ps[w][0];

  // K staging: j-independent hoist is safe (8*j ≡ 0 mod 8 in row & 7)
  const int krow_s = 32 * w + (lane >> 3);
  const int kgoff  = ((lane & 7) ^ (krow_s & 7)) * 8;
  const int vrow_r = lane >> 4;                       // 0..3

  for (int kt = 0; kt < S_ / 128; kt++) {
    __syncthreads();
    {
      const unsigned short* Kg = Kg0 + kt * 128 * DH_ + krow_s * DH_ + kgoff;
      const unsigned short* Vg = Vg0 + (size_t)(16 * w + vrow_r) * S_ + kt * 128;
#pragma unroll
      for (int j = 0; j < 4; j++)                         // K tile: 8 rows/instr
        GLDS16(Kg + 8 * j * DH_, &Ks[(32 * w + 8 * j) * 64]);
#pragma unroll
      for (int j = 0; j < 4; j++) {                       // V^T tile: 4 rows/instr
        int vgoff = (((lane & 15) ^ ((4 * j + vrow_r) & 15)) * 8);
        GLDS16(Vg + (size_t)(4 * j) * S_ + vgoff, &Vs[(16 * w + 4 * j) * 128]);
      }
    }
    __syncthreads();

    // two independent 64-col halves: S^T -> exp2+pack -> P-store(b64) -> PV
#pragma unroll
    for (int hh = 0; hh < 2; hh++) {
      f4_t sc[2][4] = {};                               // S^T: row=sk_local, col=q
#pragma unroll
      for (int ctl = 0; ctl < 4; ctl++) {
        int krow = (hh * 4 + ctl) * 16 + col;
#pragma unroll
        for (int kc = 0; kc < 2; kc++) {
          bf8_t bk = ldbf8(&Ks[krow * 64 + (((kc * 4 + quad) ^ (krow & 7)) * 8)]);
          sc[0][ctl] = MFMA16(bk, aq[0][kc], sc[0][ctl]);   // operand order: S^T
          sc[1][ctl] = MFMA16(bk, aq[1][kc], sc[1][ctl]);
        }
      }

      // exp2 + perm-pack + b64 store into Ps[q][sk] (granule ^ (q&7) swizzle)
#pragma unroll
      for (int t = 0; t < 2; t++)
#pragma unroll
        for (int ctl = 0; ctl < 4; ctl++) {
          float p0 = __builtin_amdgcn_exp2f(sc[t][ctl][0]);
          float p1 = __builtin_amdgcn_exp2f(sc[t][ctl][1]);
          float p2 = __builtin_amdgcn_exp2f(sc[t][ctl][2]);
          float p3 = __builtin_amdgcn_exp2f(sc[t][ctl][3]);
          unsigned int d0 = pkbf(p0, p1);
          unsigned int d1 = pkbf(p2, p3);
          int g = ctl * 2 + (quad >> 1);               // sk granule 0..7 within half
          unsigned short* pdst = &Pw[(t * 16 + col) * 64 + ((g ^ (col & 7)) << 3) + (quad & 1) * 4];
          *(uint2*)pdst = make_uint2(d0, d1);
        }

#pragma unroll
      for (int kcl = 0; kcl < 2; kcl++) {
        bf8_t ap0 = ldbf8(&Pw[(0 * 16 + col) * 64 + (((kcl * 4 + quad) ^ (col & 7)) << 3)]);
        bf8_t ap1 = ldbf8(&Pw[(1 * 16 + col) * 64 + (((kcl * 4 + quad) ^ (col & 7)) << 3)]);
        lacc[0] = MFMA16(ap0, vones, lacc[0]);
        lacc[1] = MFMA16(ap1, vones, lacc[1]);
        int gk = hh * 8 + kcl * 4 + quad;
#pragma unroll
        for (int cv = 0; cv < 4; cv++) {
          int vr = cv * 16 + col;
          bf8_t bv = ldbf8(&Vs[vr * 128 + ((gk ^ col) * 8)]);
          o[0][cv] = MFMA16(ap0, bv, o[0][cv]);
          o[1][cv] = MFMA16(ap1, bv, o[1][cv]);
        }
      }
    }
  }

  // epilogue: O/l -> concat (b, s, h*64+dh) bf16; lacc rows match o rows exactly.
  const int b = bh >> 4, h = bh & 15;
#pragma unroll
  for (int t = 0; t < 2; t++) {
    float linv[4];
#pragma unroll
    for (int r = 0; r < 4; r++)
      linv[r] = 1.0f / lacc[t][r];
#pragma unroll
    for (int cv = 0; cv < 4; cv++)
#pragma unroll
      for (int r = 0; r < 4; r++) {
        float v = o[t][cv][r] * linv[r];
        int s = qt * 128 + w * 32 + t * 16 + quad * 4 + r;
        int dcol = h * 64 + cv * 16 + col;
        Cc[((size_t)b * S_ + s) * D_ + dcol] = f2bf(v);
      }
  }
}

// ---------------- stage 3: output projection ----------------
// f32 epilogue via 32x128 LDS tile -> 16B/lane coalesced stores.

__global__ __launch_bounds__(256, 2) void gemm_out(const unsigned short* __restrict__ A,
    const unsigned short* __restrict__ Bt, float* __restrict__ Out)
{
  __shared__ __align__(16) unsigned short As[128 * 32];
  __shared__ __align__(16) unsigned short Bs[128 * 32];
  __shared__ __align__(16) float Cf[32 * 132];            // 16.9 KB epilogue tile
  f4_t acc[4][4] = {};
  const int bm = blockIdx.y * 128, bn = blockIdx.x * 128;
  gemm_core(A, Bt, As, Bs, bm, bn, acc);

  const int tid = threadIdx.x, w = tid >> 6, lane = tid & 63;
  const int quad = lane >> 4, col = lane & 15;
  const int wn = (w & 1) * 64;
#pragma unroll
  for (int p = 0; p < 4; p++) {
    __syncthreads();
    if ((w >> 1) == (p >> 1)) {
#pragma unroll
      for (int mi = 0; mi < 2; mi++) {
        int mt = 2 * (p & 1) + mi;
        int lr0 = mi * 16 + quad * 4;
#pragma unroll
        for (int nt = 0; nt < 4; nt++) {
          int n = wn + nt * 16 + col;
#pragma unroll
          for (int r = 0; r < 4; r++)
            Cf[(lr0 + r) * 132 + n] = acc[mt][nt][r];
        }
      }
    }
    __syncthreads();
#pragma unroll
    for (int it = 0; it < 4; it++) {
      int u = it * 256 + tid;                         // 0..1023
      int lr = u >> 5, kk4 = u & 31;
      f4_t v = *(const f4_t*)&Cf[lr * 132 + kk4 * 4];
      int g = bm + 32 * p + lr;
      *(f4_t*)&Out[(size_t)g * D_ + bn + kk4 * 4] = v;
    }
  }
}

// ---------------- launch ----------------

extern "C" void kernel_launch(void* const* d_in, const int* in_sizes, int n_in,
                              void* d_out, int out_size, void* d_ws, size_t ws_size,
                              hipStream_t stream) {
  const float* x  = (const float*)d_in[0];
  const float* Wq = (const float*)d_in[1];
  const float* Wk = (const float*)d_in[2];
  const float* Wv = (const float*)d_in[3];
  const float* Wo = (const float*)d_in[4];
  float* out = (float*)d_out;

  char* ws = (char*)d_ws;
  size_t off = 0;
  auto alloc = [&](size_t bytes) -> void* {
    void* p = ws + off;
    off += (bytes + 255) & ~(size_t)255;
    return p;
  };
  unsigned short* xb   = (unsigned short*)alloc((size_t)M_ * D_ * 2);       // 16 MB
  unsigned short* Wcat = (unsigned short*)alloc((size_t)3 * D_ * D_ * 2);   // 6 MB
  unsigned short* Wot  = (unsigned short*)alloc((size_t)D_ * D_ * 2);       // 2 MB
  unsigned short* Qb   = (unsigned short*)alloc((size_t)B_ * H_ * S_ * DH_ * 2); // 16 MB
  unsigned short* Kb   = (unsigned short*)alloc((size_t)B_ * H_ * S_ * DH_ * 2); // 16 MB
  unsigned short* Vtb  = (unsigned short*)alloc((size_t)B_ * H_ * S_ * DH_ * 2); // 16 MB
  unsigned short* Cc   = (unsigned short*)alloc((size_t)M_ * D_ * 2);       // 16 MB

  cvt_all<<<8640, 256, 0, stream>>>(x, Wq, Wk, Wv, Wo, xb, Wcat, Wot);
  gemm_qkv<<<dim3(3 * D_ / 128, M_ / 128), 256, 0, stream>>>(xb, Wcat, Qb, Kb, Vtb);
  flash_attn<<<dim3(B_ * H_, S_ / 128), 256, 0, stream>>>(Qb, Kb, Vtb, Cc);
  gemm_out<<<dim3(D_ / 128, M_ / 128), 256, 0, stream>>>(Cc, Wot, out);
}

// Round 8
// 269.878 us; speedup vs baseline: 1.5453x; 1.0074x over previous
//
#include <hip/hip_runtime.h>

// Problem constants
#define B_  4
#define S_  2048
#define D_  1024
#define H_  16
#define DH_ 64
#define M_  (B_*S_)   // 8192

typedef __bf16 bf8_t __attribute__((ext_vector_type(8)));
typedef float f4_t __attribute__((ext_vector_type(4)));
typedef unsigned short u16x8_t __attribute__((ext_vector_type(8)));

static __device__ __forceinline__ unsigned short f2bf(float f) {
  return __builtin_bit_cast(unsigned short, (__bf16)f);
}
static __device__ __forceinline__ bf8_t ldbf8(const unsigned short* p) {
  return __builtin_bit_cast(bf8_t, *(const u16x8_t*)p);
}
// pack two positive f32 -> (bf16(b)<<16)|bf16(a), round-half-up, 3 VALU ops
static __device__ __forceinline__ unsigned int pkbf(float a, float b) {
  unsigned int ua = __builtin_bit_cast(unsigned int, a) + 0x8000u;
  unsigned int ub = __builtin_bit_cast(unsigned int, b) + 0x8000u;
  return __builtin_amdgcn_perm(ub, ua, 0x07060302);
}
#define MFMA16(a,b,c) __builtin_amdgcn_mfma_f32_16x16x32_bf16((a),(b),(c),0,0,0)
#define GLDS16(gp, lp) __builtin_amdgcn_global_load_lds( \
    (const __attribute__((address_space(1))) void*)(gp), \
    (__attribute__((address_space(3))) void*)(lp), 16, 0, 0)

// 0.125 (1/sqrt(dh)) * log2(e): folded into Q so softmax uses bare exp2.
#define QSCALE 0.18033688011112042f

// ---------------- fused convert kernel ----------------
// blocks [0,8192): x->bf16 (coalesced both sides)
// blocks [8192,8576): Wq/Wk/Wv -> Wcat^T via LDS tile (64dh x 128k per block)
// blocks [8576,8640): Wo -> Wot^T via LDS tile (128x128)

__global__ void cvt_all(const float* __restrict__ x,
                        const float* __restrict__ Wq, const float* __restrict__ Wk,
                        const float* __restrict__ Wv, const float* __restrict__ Wo,
                        unsigned short* __restrict__ xb, unsigned short* __restrict__ Wcat,
                        unsigned short* __restrict__ Wot) {
  __shared__ unsigned short T[128 * 130];             // 33.3 KB, used by transpose parts
  const int blk = blockIdx.x, tid = threadIdx.x;
  if (blk < 8192) {
    int i = blk * 256 + tid;                          // over M_*D_/4
    float4 v = ((const float4*)x)[i];
    unsigned int lo = f2bf(v.x) | ((unsigned int)f2bf(v.y) << 16);
    unsigned int hi = f2bf(v.z) | ((unsigned int)f2bf(v.w) << 16);
    ((uint2*)xb)[i] = make_uint2(lo, hi);
  } else if (blk < 8576) {
    // W (H,D,DH) slab: qkv/h from bid>>3, k-chunk 128 from bid&7.
    int bid = blk - 8192;
    int qh = bid >> 3, kc = bid & 7;
    int qkv = qh >> 4, h = qh & 15;
    const float* W = (qkv == 0) ? Wq : (qkv == 1 ? Wk : Wv);
    const float* src = W + (size_t)h * 65536 + (size_t)kc * 128 * 64;
    // load 128k x 64dh coalesced -> T[k][dh] (pad 66)
#pragma unroll
    for (int jj = 0; jj < 32; jj++) {
      int idx = jj * 256 + tid;                       // kl = idx>>6, dh = idx&63
      T[(idx >> 6) * 66 + (idx & 63)] = f2bf(src[idx]);
    }
    __syncthreads();
    // gather columns -> coalesced 16B writes: Wcat[n0+dh][kc*128 + k]
    int n0 = qkv * 1024 + h * 64;
#pragma unroll
    for (int it = 0; it < 4; it++) {
      int u = it * 256 + tid;                         // 0..1023
      int dh = u >> 4, k8 = (u & 15) * 8;
      unsigned short v[8];
#pragma unroll
      for (int ii = 0; ii < 8; ii++) v[ii] = T[(k8 + ii) * 66 + dh];
      *(u16x8_t*)&Wcat[(size_t)(n0 + dh) * 1024 + kc * 128 + k8] =
          *(const u16x8_t*)v;
    }
  } else {
    // Wo (D,D) row-major -> Wot[n][k]; 128x128 tile
    int bid = blk - 8576;
    int r0 = (bid >> 3) * 128, c0 = (bid & 7) * 128;  // r0: k-dim, c0: n-dim
#pragma unroll
    for (int jj = 0; jj < 64; jj++) {
      int idx = jj * 256 + tid;                       // i = idx>>7, j = idx&127
      int i = idx >> 7, j = idx & 127;
      T[i * 130 + j] = f2bf(Wo[(size_t)(r0 + i) * 1024 + c0 + j]);
    }
    __syncthreads();
#pragma unroll
    for (int it = 0; it < 8; it++) {
      int u = it * 256 + tid;                         // 0..2047
      int j = u >> 4, i8 = (u & 15) * 8;
      unsigned short v[8];
#pragma unroll
      for (int ii = 0; ii < 8; ii++) v[ii] = T[(i8 + ii) * 130 + j];
      *(u16x8_t*)&Wot[(size_t)(c0 + j) * 1024 + r0 + i8] = *(const u16x8_t*)v;
    }
  }
}

// ---------------- GEMM core (128x128 tile, BK=32, K=1024, B^T input) ----------------

static __device__ __forceinline__ void gemm_core(const unsigned short* __restrict__ A,
    const unsigned short* __restrict__ Bt, unsigned short* As, unsigned short* Bs,
    int bm, int bn, f4_t acc[4][4])
{
  const int tid = threadIdx.x, w = tid >> 6, lane = tid & 63;
  const int quad = lane >> 4, col = lane & 15;
  const int wm = (w >> 1) * 64, wn = (w & 1) * 64;
  const int srow = lane >> 2;                         // 0..15
  const int goff = (((lane & 3) ^ ((srow >> 1) & 3)) * 8);
  const unsigned short* ga = A  + (size_t)(bm + 32 * w + srow) * D_ + goff;
  const unsigned short* gb = Bt + (size_t)(bn + 32 * w + srow) * D_ + goff;
  unsigned short* lAs0 = &As[(32 * w) * 32];
  unsigned short* lAs1 = &As[(32 * w + 16) * 32];
  unsigned short* lBs0 = &Bs[(32 * w) * 32];
  unsigned short* lBs1 = &Bs[(32 * w + 16) * 32];
  const int psw = (quad ^ ((col >> 1) & 3)) * 8;

  for (int k0 = 0; k0 < D_; k0 += 32) {
    __syncthreads();
    GLDS16(ga + k0,           lAs0);
    GLDS16(ga + 16 * D_ + k0, lAs1);
    GLDS16(gb + k0,           lBs0);
    GLDS16(gb + 16 * D_ + k0, lBs1);
    __syncthreads();
    bf8_t af[4], bfv[4];
#pragma unroll
    for (int mt = 0; mt < 4; mt++) af[mt]  = ldbf8(&As[(wm + 16 * mt + col) * 32 + psw]);
#pragma unroll
    for (int nt = 0; nt < 4; nt++) bfv[nt] = ldbf8(&Bs[(wn + 16 * nt + col) * 32 + psw]);
#pragma unroll
    for (int mt = 0; mt < 4; mt++)
#pragma unroll
      for (int nt = 0; nt < 4; nt++)
        acc[mt][nt] = MFMA16(af[mt], bfv[nt], acc[mt][nt]);
  }
}

// ---------------- stage 1: QKV projection ----------------
// qkv type is uniform per block (bn strip of 128). Q/K epilogue goes through a
// 32x128 LDS tile (4 passes) -> fully coalesced 16B/lane stores. V keeps the
// direct 8B s-contiguous store (already r-contiguous).

__global__ __launch_bounds__(256, 3) void gemm_qkv(const unsigned short* __restrict__ A,
    const unsigned short* __restrict__ Bt,
    unsigned short* __restrict__ Qp, unsigned short* __restrict__ Kp,
    unsigned short* __restrict__ Vtp)
{
  __shared__ __align__(16) unsigned short As[128 * 32];
  __shared__ __align__(16) unsigned short Bs[128 * 32];
  __shared__ __align__(16) unsigned short Cs[32 * 136];   // 8.7 KB epilogue tile
  f4_t acc[4][4] = {};
  const int bm = blockIdx.y * 128, bn = blockIdx.x * 128;
  gemm_core(A, Bt, As, Bs, bm, bn, acc);

  const int tid = threadIdx.x, w = tid >> 6, lane = tid & 63;
  const int quad = lane >> 4, col = lane & 15;
  const int wn = (w & 1) * 64;
  const int qkv = bn >> 10;

  if (qkv == 2) {
    const int wm = (w >> 1) * 64;
#pragma unroll
    for (int nt = 0; nt < 4; nt++) {
      int n = bn + wn + 16 * nt + col;
      int r1 = n & 1023, h = r1 >> 6, dh = r1 & 63;
#pragma unroll
      for (int mt = 0; mt < 4; mt++) {
        int m0 = bm + wm + 16 * mt + quad * 4;
        int b = m0 >> 11, s0 = m0 & 2047;
        unsigned int lo = f2bf(acc[mt][nt][0]) | ((unsigned int)f2bf(acc[mt][nt][1]) << 16);
        unsigned int hi = f2bf(acc[mt][nt][2]) | ((unsigned int)f2bf(acc[mt][nt][3]) << 16);
        *(uint2*)&Vtp[((size_t)(b * H_ + h) * DH_ + dh) * S_ + s0] = make_uint2(lo, hi);
      }
    }
    return;
  }

  const float qs = (qkv == 0) ? QSCALE : 1.0f;
  unsigned short* dst = (qkv == 0) ? Qp : Kp;
  const int h0 = (bn & 1023) >> 6;                    // this strip covers heads h0, h0+1
#pragma unroll
  for (int p = 0; p < 4; p++) {
    __syncthreads();
    if ((w >> 1) == (p >> 1)) {                       // 2 waves store rows [32p,32p+32)
#pragma unroll
      for (int mi = 0; mi < 2; mi++) {
        int mt = 2 * (p & 1) + mi;
        int lr0 = mi * 16 + quad * 4;
#pragma unroll
        for (int nt = 0; nt < 4; nt++) {
          int n = wn + nt * 16 + col;
#pragma unroll
          for (int r = 0; r < 4; r++)
            Cs[(lr0 + r) * 136 + n] = f2bf(acc[mt][nt][r] * qs);
        }
      }
    }
    __syncthreads();
#pragma unroll
    for (int it = 0; it < 2; it++) {
      int u = it * 256 + tid;                         // 0..511
      int lr = u >> 4, kk8 = u & 15;
      u16x8_t v = *(const u16x8_t*)&Cs[lr * 136 + kk8 * 8];
      int g = bm + 32 * p + lr;
      int b = g >> 11, s = g & 2047;
      int h = h0 + (kk8 >> 3), dh0 = (kk8 & 7) * 8;
      *(u16x8_t*)&dst[((size_t)(b * H_ + h) * S_ + s) * DH_ + dh0] = v;
    }
  }
}

// ---------------- stage 2: flash attention, S^T formulation ----------------
// grid(bh, qt): all 16 q-tiles of a head share blockIdx.x%8 -> same XCD L2.
// S^T = MFMA(K_frag, Q_frag): C row = sk (r-contiguous), col = q.
// kt body processes k-cols in FOUR independent 32-wide quarters: Ps shrinks to
// [32 q][32 sk] per wave (8KB total) -> LDS 40KB -> 4 blocks/CU (was 3).
// P packs via add+v_perm, b64 stores; l via ones-MFMA (o-row layout, no shuffles).
// Ps swizzle: granule (8 shorts; 4/row) stored at g ^ ((q>>1)&3), half-granule
// offset (quad&1)*4 kept; read un-swizzles with the same f(q). 2-way store
// aliasing (q vs q+8) unchanged from the half version.
// NOTE (R3 bug): V staging swizzle must include the per-instruction 4*j row term.

__global__ __launch_bounds__(256, 4) void flash_attn(const unsigned short* __restrict__ Qp,
    const unsigned short* __restrict__ Kp, const unsigned short* __restrict__ Vtp,
    unsigned short* __restrict__ Cc)
{
  __shared__ __align__(16) unsigned short Ks[128 * 64];   // 16 KB
  __shared__ __align__(16) unsigned short Vs[64 * 128];   // 16 KB
  __shared__ __align__(16) unsigned short Ps[4][32 * 32]; // 8 KB
  const int tid = threadIdx.x, w = tid >> 6, lane = tid & 63;
  const int quad = lane >> 4, col = lane & 15;
  const int bh = blockIdx.x, qt = blockIdx.y;

  // Q fragments straight from global (row = lane&15, k contiguous); pre-scaled.
  const unsigned short* Qg = Qp + ((size_t)bh * S_ + qt * 128 + w * 32) * DH_;
  bf8_t aq[2][2];
#pragma unroll
  for (int t = 0; t < 2; t++)
#pragma unroll
    for (int kc = 0; kc < 2; kc++)
      aq[t][kc] = ldbf8(Qg + (t * 16 + col) * DH_ + kc * 32 + quad * 8);

  const bf8_t vones = __builtin_bit_cast(bf8_t, (u16x8_t)((unsigned short)0x3F80));
  f4_t o[2][4] = {};
  f4_t lacc[2] = {};                                  // l in o-row layout via ones-MFMA

  const unsigned short* Kg0 = Kp  + (size_t)bh * S_ * DH_;
  const unsigned short* Vg0 = Vtp + (size_t)bh * DH_ * S_;
  unsigned short* Pw = &Ps[w][0];
  const int psw_f = (col >> 1) & 3;                   // Ps swizzle f(q)

  // K staging: j-independent hoist is safe (8*j ≡ 0 mod 8 in row & 7)
  const int krow_s = 32 * w + (lane >> 3);
  const int kgoff  = ((lane & 7) ^ (krow_s & 7)) * 8;
  const int vrow_r = lane >> 4;                       // 0..3

  for (int kt = 0; kt < S_ / 128; kt++) {
    __syncthreads();
    {
      const unsigned short* Kg = Kg0 + kt * 128 * DH_ + krow_s * DH_ + kgoff;
      const unsigned short* Vg = Vg0 + (size_t)(16 * w + vrow_r) * S_ + kt * 128;
#pragma unroll
      for (int j = 0; j < 4; j++)                         // K tile: 8 rows/instr
        GLDS16(Kg + 8 * j * DH_, &Ks[(32 * w + 8 * j) * 64]);
#pragma unroll
      for (int j = 0; j < 4; j++) {                       // V^T tile: 4 rows/instr
        int vgoff = (((lane & 15) ^ ((4 * j + vrow_r) & 15)) * 8);
        GLDS16(Vg + (size_t)(4 * j) * S_ + vgoff, &Vs[(16 * w + 4 * j) * 128]);
      }
    }
    __syncthreads();

    // four independent 32-col quarters: S^T -> exp2+pack -> P-store(b64) -> PV
#pragma unroll
    for (int hh = 0; hh < 4; hh++) {
      f4_t sc[2][2] = {};                               // S^T: row=sk_local, col=q
#pragma unroll
      for (int ctl = 0; ctl < 2; ctl++) {
        int krow = (hh * 2 + ctl) * 16 + col;
#pragma unroll
        for (int kc = 0; kc < 2; kc++) {
          bf8_t bk = ldbf8(&Ks[krow * 64 + (((kc * 4 + quad) ^ (krow & 7)) * 8)]);
          sc[0][ctl] = MFMA16(bk, aq[0][kc], sc[0][ctl]);   // operand order: S^T
          sc[1][ctl] = MFMA16(bk, aq[1][kc], sc[1][ctl]);
        }
      }

      // exp2 + perm-pack + b64 store into Ps[q][sk] (granule ^ f(q) swizzle)
#pragma unroll
      for (int t = 0; t < 2; t++)
#pragma unroll
        for (int ctl = 0; ctl < 2; ctl++) {
          float p0 = __builtin_amdgcn_exp2f(sc[t][ctl][0]);
          float p1 = __builtin_amdgcn_exp2f(sc[t][ctl][1]);
          float p2 = __builtin_amdgcn_exp2f(sc[t][ctl][2]);
          float p3 = __builtin_amdgcn_exp2f(sc[t][ctl][3]);
          unsigned int d0 = pkbf(p0, p1);
          unsigned int d1 = pkbf(p2, p3);
          int g = ctl * 2 + (quad >> 1);               // sk granule 0..3 within quarter
          unsigned short* pdst = &Pw[(t * 16 + col) * 32 + ((g ^ psw_f) << 3) + (quad & 1) * 4];
          *(uint2*)pdst = make_uint2(d0, d1);
        }

      // PV: one K=32 step per quarter
      {
        bf8_t ap0 = ldbf8(&Pw[(0 * 16 + col) * 32 + ((quad ^ psw_f) << 3)]);
        bf8_t ap1 = ldbf8(&Pw[(1 * 16 + col) * 32 + ((quad ^ psw_f) << 3)]);
        lacc[0] = MFMA16(ap0, vones, lacc[0]);
        lacc[1] = MFMA16(ap1, vones, lacc[1]);
        int gk = hh * 4 + quad;                        // Vs sk granule 0..15
#pragma unroll
        for (int cv = 0; cv < 4; cv++) {
          int vr = cv * 16 + col;
          bf8_t bv = ldbf8(&Vs[vr * 128 + ((gk ^ col) * 8)]);
          o[0][cv] = MFMA16(ap0, bv, o[0][cv]);
          o[1][cv] = MFMA16(ap1, bv, o[1][cv]);
        }
      }
    }
  }

  // epilogue: O/l -> concat (b, s, h*64+dh) bf16; lacc rows match o rows exactly.
  const int b = bh >> 4, h = bh & 15;
#pragma unroll
  for (int t = 0; t < 2; t++) {
    float linv[4];
#pragma unroll
    for (int r = 0; r < 4; r++)
      linv[r] = 1.0f / lacc[t][r];
#pragma unroll
    for (int cv = 0; cv < 4; cv++)
#pragma unroll
      for (int r = 0; r < 4; r++) {
        float v = o[t][cv][r] * linv[r];
        int s = qt * 128 + w * 32 + t * 16 + quad * 4 + r;
        int dcol = h * 64 + cv * 16 + col;
        Cc[((size_t)b * S_ + s) * D_ + dcol] = f2bf(v);
      }
  }
}

// ---------------- stage 3: output projection ----------------
// f32 epilogue via 32x128 LDS tile -> 16B/lane coalesced stores.

__global__ __launch_bounds__(256, 3) void gemm_out(const unsigned short* __restrict__ A,
    const unsigned short* __restrict__ Bt, float* __restrict__ Out)
{
  __shared__ __align__(16) unsigned short As[128 * 32];
  __shared__ __align__(16) unsigned short Bs[128 * 32];
  __shared__ __align__(16) float Cf[32 * 132];            // 16.9 KB epilogue tile
  f4_t acc[4][4] = {};
  const int bm = blockIdx.y * 128, bn = blockIdx.x * 128;
  gemm_core(A, Bt, As, Bs, bm, bn, acc);

  const int tid = threadIdx.x, w = tid >> 6, lane = tid & 63;
  const int quad = lane >> 4, col = lane & 15;
  const int wn = (w & 1) * 64;
#pragma unroll
  for (int p = 0; p < 4; p++) {
    __syncthreads();
    if ((w >> 1) == (p >> 1)) {
#pragma unroll
      for (int mi = 0; mi < 2; mi++) {
        int mt = 2 * (p & 1) + mi;
        int lr0 = mi * 16 + quad * 4;
#pragma unroll
        for (int nt = 0; nt < 4; nt++) {
          int n = wn + nt * 16 + col;
#pragma unroll
          for (int r = 0; r < 4; r++)
            Cf[(lr0 + r) * 132 + n] = acc[mt][nt][r];
        }
      }
    }
    __syncthreads();
#pragma unroll
    for (int it = 0; it < 4; it++) {
      int u = it * 256 + tid;                         // 0..1023
      int lr = u >> 5, kk4 = u & 31;
      f4_t v = *(const f4_t*)&Cf[lr * 132 + kk4 * 4];
      int g = bm + 32 * p + lr;
      *(f4_t*)&Out[(size_t)g * D_ + bn + kk4 * 4] = v;
    }
  }
}

// ---------------- launch ----------------

extern "C" void kernel_launch(void* const* d_in, const int* in_sizes, int n_in,
                              void* d_out, int out_size, void* d_ws, size_t ws_size,
                              hipStream_t stream) {
  const float* x  = (const float*)d_in[0];
  const float* Wq = (const float*)d_in[1];
  const float* Wk = (const float*)d_in[2];
  const float* Wv = (const float*)d_in[3];
  const float* Wo = (const float*)d_in[4];
  float* out = (float*)d_out;

  char* ws = (char*)d_ws;
  size_t off = 0;
  auto alloc = [&](size_t bytes) -> void* {
    void* p = ws + off;
    off += (bytes + 255) & ~(size_t)255;
    return p;
  };
  unsigned short* xb   = (unsigned short*)alloc((size_t)M_ * D_ * 2);       // 16 MB
  unsigned short* Wcat = (unsigned short*)alloc((size_t)3 * D_ * D_ * 2);   // 6 MB
  unsigned short* Wot  = (unsigned short*)alloc((size_t)D_ * D_ * 2);       // 2 MB
  unsigned short* Qb   = (unsigned short*)alloc((size_t)B_ * H_ * S_ * DH_ * 2); // 16 MB
  unsigned short* Kb   = (unsigned short*)alloc((size_t)B_ * H_ * S_ * DH_ * 2); // 16 MB
  unsigned short* Vtb  = (unsigned short*)alloc((size_t)B_ * H_ * S_ * DH_ * 2); // 16 MB
  unsigned short* Cc   = (unsigned short*)alloc((size_t)M_ * D_ * 2);       // 16 MB

  cvt_all<<<8640, 256, 0, stream>>>(x, Wq, Wk, Wv, Wo, xb, Wcat, Wot);
  gemm_qkv<<<dim3(3 * D_ / 128, M_ / 128), 256, 0, stream>>>(xb, Wcat, Qb, Kb, Vtb);
  flash_attn<<<dim3(B_ * H_, S_ / 128), 256, 0, stream>>>(Qb, Kb, Vtb, Cc);
  gemm_out<<<dim3(D_ / 128, M_ / 128), 256, 0, stream>>>(Cc, Wot, out);
}